// Round 12
// baseline (341.866 us; speedup 1.0000x reference)
//
#include <hip/hip_runtime.h>

#define B_ 4
#define T_ 1024
#define HID_ 1024
#define H_ 8
#define CONV_DIM_ 3072
#define MROWS (B_*T_)

typedef __bf16 bf16x8 __attribute__((ext_vector_type(8)));
typedef float f32x4 __attribute__((ext_vector_type(4)));

#define MFMA16(a,b,c) __builtin_amdgcn_mfma_f32_16x16x32_bf16((a),(b),(c),0,0,0)

static __device__ __forceinline__ unsigned short f2bf(float f) {
  unsigned u = __float_as_uint(f);
  unsigned r = u + 0x7fffu + ((u >> 16) & 1u);   // RNE
  return (unsigned short)(r >> 16);
}
static __device__ __forceinline__ float bfu2f(unsigned short v) {
  return __uint_as_float(((unsigned)v) << 16);
}
static __device__ __forceinline__ float4 recon4(ushort4 h, ushort4 l) {
  float4 r;
  r.x = bfu2f(h.x) + bfu2f(l.x);
  r.y = bfu2f(h.y) + bfu2f(l.y);
  r.z = bfu2f(h.z) + bfu2f(l.z);
  r.w = bfu2f(h.w) + bfu2f(l.w);
  return r;
}

// async global->LDS 16B. LDS dest must be wave-uniform base + lane*16 (m104/m108).
static __device__ __forceinline__ void gld16(void* lds, const void* g) {
  __builtin_amdgcn_global_load_lds(
      (const __attribute__((address_space(1))) unsigned int*)g,
      (__attribute__((address_space(3))) unsigned int*)lds, 16, 0, 0);
}

// Merged weight conversions: qkv_w -> hi/lo split (blocks 0..3071),
// z_w -> bf16 (3072..4095), out_w -> bf16 (4096..5119).
__global__ __launch_bounds__(256) void convert_weights_kernel(
    const float* __restrict__ qkv_w, const float* __restrict__ z_w,
    const float* __restrict__ out_w,
    unsigned short* __restrict__ wc_hi, unsigned short* __restrict__ wc_lo,
    unsigned short* __restrict__ wz_bf, unsigned short* __restrict__ outw_bf) {
  const int bid = blockIdx.x;
  const int tid = threadIdx.x;
  if (bid < 3072) {
    int i = (bid * 256 + tid) * 4;
    float4 v = *(const float4*)(qkv_w + i);
    ushort4 h, l;
    h.x = f2bf(v.x); h.y = f2bf(v.y); h.z = f2bf(v.z); h.w = f2bf(v.w);
    l.x = f2bf(v.x - bfu2f(h.x));
    l.y = f2bf(v.y - bfu2f(h.y));
    l.z = f2bf(v.z - bfu2f(h.z));
    l.w = f2bf(v.w - bfu2f(h.w));
    *(ushort4*)(wc_hi + i) = h;
    *(ushort4*)(wc_lo + i) = l;
  } else {
    const bool isZ = (bid < 4096);
    const float* src = isZ ? z_w : out_w;
    unsigned short* dst = isZ ? wz_bf : outw_bf;
    int i = (((bid - (isZ ? 3072 : 4096)) * 256) + tid) * 4;
    float4 v = *(const float4*)(src + i);
    ushort4 o;
    o.x = f2bf(v.x); o.y = f2bf(v.y); o.z = f2bf(v.z); o.w = f2bf(v.w);
    *(ushort4*)(dst + i) = o;
  }
}

// Single-pass bf16 MFMA GEMM: C[M,N] = A[M,K] * W[N,K]^T. 128x128 tile, BK=32.
template<int OUT_BF16>
__global__ __launch_bounds__(256) void gemm_mfma_kernel(
    const unsigned short* __restrict__ A, const unsigned short* __restrict__ W,
    void* __restrict__ Cv, int M, int N, int K) {
  __shared__ __align__(16) unsigned short lA[128*32];
  __shared__ __align__(16) unsigned short lB[128*32];
  const int tid  = threadIdx.x;
  const int lane = tid & 63;
  const int wv   = tid >> 6;
  const int wm   = (wv >> 1) * 64;
  const int wn   = (wv & 1) * 64;
  const int m16  = lane & 15;
  const int quad = lane >> 4;
  const int bm = blockIdx.y * 128;
  const int bn = blockIdx.x * 128;

  f32x4 acc[4][4];
  #pragma unroll
  for (int i = 0; i < 4; ++i)
    #pragma unroll
    for (int j = 0; j < 4; ++j)
      acc[i][j] = (f32x4){0.f, 0.f, 0.f, 0.f};

  const int r0 = tid >> 2, c0 = tid & 3;
  const int r1 = r0 + 64;
  const int g0 = (c0 ^ (r0 & 3)) * 8;
  const int g1 = (c0 ^ (r1 & 3)) * 8;
  const unsigned short* Ar0 = A + (size_t)(bm + r0) * K + g0;
  const unsigned short* Ar1 = A + (size_t)(bm + r1) * K + g1;
  const unsigned short* Wr0 = W + (size_t)(bn + r0) * K + g0;
  const unsigned short* Wr1 = W + (size_t)(bn + r1) * K + g1;
  unsigned short* sA0 = &lA[(size_t)tid * 8];
  unsigned short* sA1 = &lA[(size_t)(tid + 256) * 8];
  unsigned short* sB0 = &lB[(size_t)tid * 8];
  unsigned short* sB1 = &lB[(size_t)(tid + 256) * 8];

  int offA[4], offB[4];
  #pragma unroll
  for (int i = 0; i < 4; ++i) {
    int ra = wm + i * 16 + m16;
    offA[i] = ra * 32 + (quad ^ (ra & 3)) * 8;
    int rb = wn + i * 16 + m16;
    offB[i] = rb * 32 + (quad ^ (rb & 3)) * 8;
  }

  for (int k0 = 0; k0 < K; k0 += 32) {
    gld16(sA0, Ar0 + k0);
    gld16(sA1, Ar1 + k0);
    gld16(sB0, Wr0 + k0);
    gld16(sB1, Wr1 + k0);
    __syncthreads();
    bf16x8 af[4], bfr[4];
    #pragma unroll
    for (int i = 0; i < 4; ++i) {
      af[i]  = *(const bf16x8*)&lA[offA[i]];
      bfr[i] = *(const bf16x8*)&lB[offB[i]];
    }
    #pragma unroll
    for (int mi = 0; mi < 4; ++mi)
      #pragma unroll
      for (int ni = 0; ni < 4; ++ni)
        acc[mi][ni] = MFMA16(af[mi], bfr[ni], acc[mi][ni]);
    __syncthreads();
  }

  #pragma unroll
  for (int mi = 0; mi < 4; ++mi) {
    #pragma unroll
    for (int r = 0; r < 4; ++r) {
      size_t row = (size_t)(bm + wm + mi * 16 + quad * 4 + r);
      #pragma unroll
      for (int ni = 0; ni < 4; ++ni) {
        int col = bn + wn + ni * 16 + m16;
        float val = acc[mi][ni][r];
        if (OUT_BF16) ((unsigned short*)Cv)[row * N + col] = f2bf(val);
        else          ((float*)Cv)[row * N + col] = val;
      }
    }
  }
}

// Fused: split-precision MFMA GEMM (mixed = hs.qkv_w^T, 3 products) + causal
// depthwise conv (K=4) epilogue. mixed NEVER goes to HBM.
// NOTE (round-11 lesson): the Alo.Whi term is REQUIRED — dropping it gave
// absmax 0.18 (the scan recurrence amplifies q/k operand error ~100x).
// Epilogue: two 64-row half-tiles through [64][132] fp32 LDS (35328B total).
__global__ __launch_bounds__(256) void gemm_split_conv_kernel(
    const unsigned short* __restrict__ Ahi, const unsigned short* __restrict__ Alo,
    const unsigned short* __restrict__ Whi, const unsigned short* __restrict__ Wlo,
    const float* __restrict__ conv_w,
    unsigned short* __restrict__ qhi, unsigned short* __restrict__ qlo,
    unsigned short* __restrict__ khi, unsigned short* __restrict__ klo,
    float* __restrict__ vb, float* __restrict__ edge) {
  // LDS union: 4 staging tiles (32768B) during K-loop; epilogue: smX2 [64][132]
  // fp32 (33792B) + carry [3][128] fp32 (1536B) = 35328B total.
  __shared__ __align__(16) unsigned char ldsraw[64*132*4 + 3*128*4];
  unsigned short* lAh = (unsigned short*)ldsraw;
  unsigned short* lAl = lAh + 128*32;
  unsigned short* lBh = lAl + 128*32;
  unsigned short* lBl = lBh + 128*32;
  float* smX2  = (float*)ldsraw;
  float* carry = (float*)(ldsraw + 64*132*4);

  const int tid  = threadIdx.x;
  const int lane = tid & 63;
  const int wv   = tid >> 6;
  const int wm   = (wv >> 1) * 64;
  const int wn   = (wv & 1) * 64;
  const int m16  = lane & 15;
  const int quad = lane >> 4;
  const int bm = blockIdx.y * 128;
  const int bn = blockIdx.x * 128;

  f32x4 acc[4][4];
  #pragma unroll
  for (int i = 0; i < 4; ++i)
    #pragma unroll
    for (int j = 0; j < 4; ++j)
      acc[i][j] = (f32x4){0.f, 0.f, 0.f, 0.f};

  const int r0 = tid >> 2, c0 = tid & 3;
  const int r1 = r0 + 64;
  const int g0 = (c0 ^ (r0 & 3)) * 8;
  const int g1 = (c0 ^ (r1 & 3)) * 8;
  const size_t oA0 = (size_t)(bm + r0) * 1024 + g0;
  const size_t oA1 = (size_t)(bm + r1) * 1024 + g1;
  const size_t oB0 = (size_t)(bn + r0) * 1024 + g0;
  const size_t oB1 = (size_t)(bn + r1) * 1024 + g1;
  const int s0 = tid * 8, s1 = (tid + 256) * 8;

  int offA[4], offB[4];
  #pragma unroll
  for (int i = 0; i < 4; ++i) {
    int ra = wm + i * 16 + m16;
    offA[i] = ra * 32 + (quad ^ (ra & 3)) * 8;
    int rb = wn + i * 16 + m16;
    offB[i] = rb * 32 + (quad ^ (rb & 3)) * 8;
  }

  for (int k0 = 0; k0 < 1024; k0 += 32) {
    gld16(&lAh[s0], Ahi + oA0 + k0);
    gld16(&lAh[s1], Ahi + oA1 + k0);
    gld16(&lAl[s0], Alo + oA0 + k0);
    gld16(&lAl[s1], Alo + oA1 + k0);
    gld16(&lBh[s0], Whi + oB0 + k0);
    gld16(&lBh[s1], Whi + oB1 + k0);
    gld16(&lBl[s0], Wlo + oB0 + k0);
    gld16(&lBl[s1], Wlo + oB1 + k0);
    __syncthreads();
    bf16x8 afh[4], bfh[4];
    #pragma unroll
    for (int i = 0; i < 4; ++i) {
      afh[i] = *(const bf16x8*)&lAh[offA[i]];
      bfh[i] = *(const bf16x8*)&lBh[offB[i]];
    }
    #pragma unroll
    for (int mi = 0; mi < 4; ++mi)
      #pragma unroll
      for (int ni = 0; ni < 4; ++ni)
        acc[mi][ni] = MFMA16(afh[mi], bfh[ni], acc[mi][ni]);
    {
      bf16x8 bfl[4];
      #pragma unroll
      for (int i = 0; i < 4; ++i) bfl[i] = *(const bf16x8*)&lBl[offB[i]];
      #pragma unroll
      for (int mi = 0; mi < 4; ++mi)
        #pragma unroll
        for (int ni = 0; ni < 4; ++ni)
          acc[mi][ni] = MFMA16(afh[mi], bfl[ni], acc[mi][ni]);
    }
    {
      bf16x8 afl[4];
      #pragma unroll
      for (int i = 0; i < 4; ++i) afl[i] = *(const bf16x8*)&lAl[offA[i]];
      #pragma unroll
      for (int mi = 0; mi < 4; ++mi)
        #pragma unroll
        for (int ni = 0; ni < 4; ++ni)
          acc[mi][ni] = MFMA16(afl[mi], bfh[ni], acc[mi][ni]);
    }
    __syncthreads();   // last iter: all staging reads done -> smX2 alias safe
  }

  // ---- epilogue: two 64-row half-tiles
  const int bi = blockIdx.y;
  const int c  = tid & 127;
  const int rh = tid >> 7;
  const int cg = bn + c;
  const int part = cg >> 10;         // block-uniform
  const int hh = (cg & 1023) >> 7;   // block-uniform
  const int b = bm >> 10;
  const int tloc0 = bm & 1023;
  float4 w4 = *(const float4*)(conv_w + cg * 4);
  size_t rowb = ((size_t)(b * H_ + hh)) * T_;
  unsigned short* dh = (part == 0) ? qhi : khi;
  unsigned short* dl = (part == 0) ? qlo : klo;

  #pragma unroll
  for (int half = 0; half < 2; ++half) {
    if (half == 1) __syncthreads();   // half-0 conv reads + carry save done
    // write this half's acc rows into smX2 (local rows 0..63)
    if ((wv >> 1) == half) {
      #pragma unroll
      for (int mi = 0; mi < 4; ++mi)
        #pragma unroll
        for (int r = 0; r < 4; ++r) {
          int row = mi * 16 + quad * 4 + r;
          #pragma unroll
          for (int ni = 0; ni < 4; ++ni)
            smX2[row * 132 + wn + ni * 16 + m16] = acc[mi][ni][r];
        }
    }
    __syncthreads();
    // edge spill + (half 0) carry save — 384 items via e*256+tid (256 threads)
    if (half == 0) {
      #pragma unroll
      for (int e = 0; e < 2; ++e) {
        int idx = e * 256 + tid;
        int r = idx >> 7, cc = idx & 127;
        if (r < 3) {
          edge[((size_t)bi*6 + 3 + r)*3072 + bn + cc] = smX2[r*132 + cc];
          carry[r*128 + cc] = smX2[(61+r)*132 + cc];
        }
      }
    } else {
      if (bi < 31) {
        #pragma unroll
        for (int e = 0; e < 2; ++e) {
          int idx = e * 256 + tid;
          int r = idx >> 7, cc = idx & 127;
          if (r < 3)
            edge[((size_t)(bi+1)*6 + r)*3072 + bn + cc] = smX2[(61+r)*132 + cc];
        }
      }
    }
    // conv: 2 threads/col, 32 t-steps each
    {
      const int tb0 = rh * 32;
      float x0, x1, x2;
      if (tb0 >= 3) {
        x0 = smX2[(tb0-3)*132 + c];
        x1 = smX2[(tb0-2)*132 + c];
        x2 = smX2[(tb0-1)*132 + c];
      } else {  // tb0 == 0
        if (half == 0) { x0 = 0.f; x1 = 0.f; x2 = 0.f; }
        else { x0 = carry[0*128 + c]; x1 = carry[1*128 + c]; x2 = carry[2*128 + c]; }
      }
      for (int tt = 0; tt < 32; ++tt) {
        const int t = tb0 + tt;
        float x3 = smX2[t*132 + c];
        float s = fmaf(w4.x, x0, fmaf(w4.y, x1, fmaf(w4.z, x2, w4.w * x3)));
        x0 = x1; x1 = x2; x2 = x3;
        const int tg = tloc0 + half*64 + t;
        if (part == 2) {
          vb[(rowb + tg) * 128 + c] = s;
        } else {
          int sw = (((c >> 3) ^ (tg & 7)) << 3) + (c & 7);
          unsigned short hv = f2bf(s);
          dh[(rowb + tg) * 128 + sw] = hv;
          dl[(rowb + tg) * 128 + sw] = f2bf(s - bfu2f(hv));
        }
      }
    }
  }
}

// Boundary fixup (trivial): 6 mixed rows come straight from the edge buffer.
__global__ __launch_bounds__(128) void conv_fix_kernel(
    const float* __restrict__ edge, const float* __restrict__ conv_w,
    unsigned short* __restrict__ qhi, unsigned short* __restrict__ qlo,
    unsigned short* __restrict__ khi, unsigned short* __restrict__ klo,
    float* __restrict__ vb) {
  const int bi = blockIdx.x / 24;
  const int cb = blockIdx.x % 24;
  const int bm = bi * 128, n0 = cb * 128;
  const int b = bm >> 10, tloc = bm & 1023;
  const int c = threadIdx.x;
  const int cg = n0 + c;
  float m[6];
  #pragma unroll
  for (int j = 0; j < 6; ++j)
    m[j] = edge[((size_t)bi*6 + j)*3072 + cg];
  if (tloc == 0) { m[0] = 0.f; m[1] = 0.f; m[2] = 0.f; }
  const int part = cg >> 10;
  const int hh = (cg & 1023) >> 7;
  float4 w4 = *(const float4*)(conv_w + cg * 4);
  size_t rowb = ((size_t)(b * H_ + hh)) * T_;
  unsigned short* dh = (part == 0) ? qhi : khi;
  unsigned short* dl = (part == 0) ? qlo : klo;
  #pragma unroll
  for (int jo = 0; jo < 3; ++jo) {
    float s = fmaf(w4.x, m[jo], fmaf(w4.y, m[jo+1],
              fmaf(w4.z, m[jo+2], w4.w * m[jo+3])));
    const int tg = tloc + jo;
    if (part == 2) {
      vb[(rowb + tg) * 128 + c] = s;
    } else {
      int sw = (((c >> 3) ^ (tg & 7)) << 3) + (c & 7);
      unsigned short hv = f2bf(s);
      dh[(rowb + tg) * 128 + sw] = hv;
      dl[(rowb + tg) * 128 + sw] = f2bf(s - bfu2f(hv));
    }
  }
}

// bb/aa projections fused with beta / g=log(alpha). Reads fp32 hs (exact).
// ALSO emits hs as bf16 hi/lo via a separate COALESCED all-thread pass.
__global__ __launch_bounds__(128) void proj_ba_kernel(
    const float* __restrict__ hs, const float* __restrict__ b_w, const float* __restrict__ a_w,
    const float* __restrict__ dt_bias, const float* __restrict__ A_log,
    float* __restrict__ gout, float* __restrict__ beta,
    unsigned short* __restrict__ hs_hi, unsigned short* __restrict__ hs_lo) {
  const int bt = blockIdx.x;
  const int b = bt >> 10;
  const int t = bt & 1023;
  const int tid = threadIdx.x;
  const int grp = tid >> 3;
  const int l8 = tid & 7;
  const int h = grp & 7;
  const bool isA = grp >= 8;
  const float* w = (isA ? a_w : b_w) + (size_t)h * HID_;
  const float* x = hs + (size_t)bt * HID_;
  // coalesced hs -> bf16 hi/lo emit: 128 threads x 8 elems
  {
    const int e = tid * 8;
    float4 xv0 = *(const float4*)(x + e);
    float4 xv1 = *(const float4*)(x + e + 4);
    ushort4 h0, l0, h1, l1;
    h0.x = f2bf(xv0.x); h0.y = f2bf(xv0.y); h0.z = f2bf(xv0.z); h0.w = f2bf(xv0.w);
    l0.x = f2bf(xv0.x - bfu2f(h0.x)); l0.y = f2bf(xv0.y - bfu2f(h0.y));
    l0.z = f2bf(xv0.z - bfu2f(h0.z)); l0.w = f2bf(xv0.w - bfu2f(h0.w));
    h1.x = f2bf(xv1.x); h1.y = f2bf(xv1.y); h1.z = f2bf(xv1.z); h1.w = f2bf(xv1.w);
    l1.x = f2bf(xv1.x - bfu2f(h1.x)); l1.y = f2bf(xv1.y - bfu2f(h1.y));
    l1.z = f2bf(xv1.z - bfu2f(h1.z)); l1.w = f2bf(xv1.w - bfu2f(h1.w));
    unsigned short* hho = hs_hi + (size_t)bt * HID_ + e;
    unsigned short* hlo = hs_lo + (size_t)bt * HID_ + e;
    *(ushort4*)hho = h0;       *(ushort4*)hlo = l0;
    *(ushort4*)(hho + 4) = h1; *(ushort4*)(hlo + 4) = l1;
  }
  float s = 0.f;
  for (int e = l8*4; e < HID_; e += 32){
    float4 xv = *(const float4*)(x + e);
    float4 wv = *(const float4*)(w + e);
    s = fmaf(xv.x, wv.x, s);
    s = fmaf(xv.y, wv.y, s);
    s = fmaf(xv.z, wv.z, s);
    s = fmaf(xv.w, wv.w, s);
  }
  s += __shfl_xor(s,1); s += __shfl_xor(s,2); s += __shfl_xor(s,4);
  if (l8 == 0) {
    size_t o = ((size_t)(b*H_ + h))*T_ + t;
    if (!isA) {
      beta[o] = 1.f/(1.f+expf(-s));
    } else {
      float xx = s + dt_bias[h];
      float sp = fmaxf(xx,0.f) + log1pf(expf(-fabsf(xx)));   // softplus
      gout[o] = -expf(A_log[h]) * sp;                        // g = log(alpha)
    }
  }
}

// Parallel precompute: 512 blocks = (bh, chunk). MFMA version.
// T = (I+A)^-1 (unit lower), B = incl-lower decayed QK^T.
// K.K^T and Q.K^T on matrix cores (hi/lo 3-chain split), fragments loaded
// directly from the pre-swizzled global buffers. Upper-triangle tiles
// written as ZEROS. Inversion chain unchanged.
__global__ __launch_bounds__(256) void scan_ab_kernel(
    const unsigned short* __restrict__ qhi_g, const unsigned short* __restrict__ qlo_g,
    const unsigned short* __restrict__ khi_g, const unsigned short* __restrict__ klo_g,
    const float* __restrict__ gbuf, const float* __restrict__ bbuf,
    unsigned short* __restrict__ Thi_g, unsigned short* __restrict__ Tlo_g,
    unsigned short* __restrict__ Bhi_g, unsigned short* __restrict__ Blo_g) {
  const int blk = blockIdx.x;
  const int bh = blk >> 4;
  const int ch = blk & 15;
  const int t0 = ch * 64;
  const int tid = threadIdx.x;
  const int wvb = tid >> 6;          // wave = output row-block
  const int lane = tid & 63;
  const int v16 = lane & 15;
  const int quad = lane >> 4;
  __shared__ float sAA[64][68];
  __shared__ float lL[64];
  __shared__ float bL[64];
  unsigned short* Tho = Thi_g + (size_t)blk*4096;
  unsigned short* Tlo = Tlo_g + (size_t)blk*4096;
  unsigned short* Bho = Bhi_g + (size_t)blk*4096;
  unsigned short* Blo = Blo_g + (size_t)blk*4096;
  const unsigned short* kh  = khi_g + (size_t)bh*131072 + (size_t)t0*128;
  const unsigned short* klp = klo_g + (size_t)bh*131072 + (size_t)t0*128;
  const unsigned short* qh  = qhi_g + (size_t)bh*131072 + (size_t)t0*128;
  const unsigned short* qlp = qlo_g + (size_t)bh*131072 + (size_t)t0*128;

  if (tid < 64) {
    float x = gbuf[(size_t)bh*T_ + t0 + tid];
    #pragma unroll
    for (int o = 1; o < 64; o <<= 1) {
      float y = __shfl_up(x, o);
      if (tid >= o) x += y;
    }
    lL[tid] = x;
    bL[tid] = bbuf[(size_t)bh*T_ + t0 + tid];
  }

  const int ar = wvb*16 + v16;
  const int arx = ar & 7;
  bf16x8 kAh[4], kAl[4], qAh[4], qAl[4];
  #pragma unroll
  for (int ks = 0; ks < 4; ++ks) {
    const int u = 4*ks + quad;
    const int ao = ar*128 + ((u ^ arx) << 3);
    kAh[ks] = *(const bf16x8*)&kh[ao];
    kAl[ks] = *(const bf16x8*)&klp[ao];
    qAh[ks] = *(const bf16x8*)&qh[ao];
    qAl[ks] = *(const bf16x8*)&qlp[ao];
  }
  __syncthreads();   // lL/bL ready

  const int i0 = wvb*16 + quad*4;
  float biv[4], liv[4];
  #pragma unroll
  for (int r = 0; r < 4; ++r) { biv[r] = bL[i0+r]; liv[r] = lL[i0+r]; }

  #pragma unroll
  for (int cb = 0; cb < 4; ++cb) {
    const int j = cb*16 + v16;
    if (cb <= wvb) {
      const int rb = cb*16 + v16;
      const int rbx = rb & 7;
      f32x4 a1 = (f32x4){0.f,0.f,0.f,0.f}, a2 = (f32x4){0.f,0.f,0.f,0.f};
      f32x4 q1 = (f32x4){0.f,0.f,0.f,0.f}, q2 = (f32x4){0.f,0.f,0.f,0.f};
      #pragma unroll
      for (int ks = 0; ks < 4; ++ks) {
        const int u = 4*ks + quad;
        const int bo = rb*128 + ((u ^ rbx) << 3);
        bf16x8 bhv = *(const bf16x8*)&kh[bo];
        bf16x8 blv = *(const bf16x8*)&klp[bo];
        a1 = MFMA16(kAh[ks], bhv, a1);
        a2 = MFMA16(kAh[ks], blv, a2);
        a2 = MFMA16(kAl[ks], bhv, a2);
        q1 = MFMA16(qAh[ks], bhv, q1);
        q2 = MFMA16(qAh[ks], blv, q2);
        q2 = MFMA16(qAl[ks], bhv, q2);
      }
      float lj = lL[j];
      #pragma unroll
      for (int r = 0; r < 4; ++r) {
        const int i = i0 + r;
        float av = a1[r] + a2[r];
        float qv = q1[r] + q2[r];
        sAA[i][j] = (j < i) ? biv[r] * __expf(liv[r] - lj) * av : 0.f;
        float xq = (j <= i) ? __expf(liv[r] - lj) * qv : 0.f;
        unsigned short hv = f2bf(xq);
        int sidx = i*64 + (((j>>3) ^ (i&7)) << 3) + (j&7);
        Bho[sidx] = hv;
        Blo[sidx] = f2bf(xq - bfu2f(hv));
      }
    } else {
      #pragma unroll
      for (int r = 0; r < 4; ++r) {
        const int i = i0 + r;
        sAA[i][j] = 0.f;
        int sidx = i*64 + (((j>>3) ^ (i&7)) << 3) + (j&7);
        Bho[sidx] = 0;
        Blo[sidx] = 0;
      }
    }
  }
  __syncthreads();

  // invert (I+A): 4 waves x 16 cols, rows rr+4m per thread; wave-local chain
  {
    const int w = tid >> 6;
    const int ln = tid & 63;
    const int colc = w*16 + (ln & 15);
    const int rr = ln >> 4;
    float rh[16];
    #pragma unroll
    for (int m=0;m<16;++m) rh[m] = (rr + 4*m == colc) ? 1.f : 0.f;
    for (int j = 0; j < 63; ++j) {
      int src = ((j & 3) << 4) | (ln & 15);
      float wj = __shfl(rh[j >> 2], src);
      #pragma unroll
      for (int m=0;m<16;++m)
        rh[m] = fmaf(-sAA[rr + 4*m][j], wj, rh[m]);
    }
    #pragma unroll
    for (int m=0;m<16;++m) {
      int i2 = rr + 4*m;
      float x = rh[m];
      unsigned short hv = f2bf(x);
      int sidx = i2*64 + (((colc>>3) ^ (i2&7)) << 3) + (colc&7);
      Tho[sidx] = hv;
      Tlo[sidx] = f2bf(x - bfu2f(hv));
    }
  }
}

// Sequential chunked scan, 512 threads (8 waves), UT-transform, all-MFMA phases.
// XCD-aware block decode: bh = bid&31, sl = bid>>5.
__global__ __launch_bounds__(512) void scan_seq_kernel(
    const unsigned short* __restrict__ khi_g, const unsigned short* __restrict__ klo_g,
    const unsigned short* __restrict__ qhi_g, const unsigned short* __restrict__ qlo_g,
    const float* __restrict__ vb,
    const float* __restrict__ gbuf, const float* __restrict__ bbuf,
    const unsigned short* __restrict__ Thi_g, const unsigned short* __restrict__ Tlo_g,
    const unsigned short* __restrict__ Bhi_g, const unsigned short* __restrict__ Blo_g,
    float* __restrict__ ob) {
  const int bh = blockIdx.x & 31;
  const int sl = blockIdx.x >> 5;
  const int tid = threadIdx.x;
  const int wv = tid >> 6;
  const int lane = tid & 63;
  const int v16 = lane & 15;
  const int quad = lane >> 4;
  const int tb = (wv & 3) * 16;
  const bool isQ = (wv >= 4);
  const int vx = v16 & 7;

  __shared__ __align__(16) unsigned short KhiL[2][64*128];
  __shared__ __align__(16) unsigned short KloL[2][64*128];
  __shared__ __align__(16) unsigned short WTh[16*64],  WTl[16*64];
  __shared__ __align__(16) unsigned short W2Th[16*64], W2Tl[16*64];
  __shared__ __align__(16) unsigned short W3Th[16*64], W3Tl[16*64];
  __shared__ __align__(16) unsigned short S0h[16*128], S0l[16*128];

  const unsigned short* kh  = khi_g + (size_t)bh*131072;
  const unsigned short* klp = klo_g + (size_t)bh*131072;
  const unsigned short* qh  = qhi_g + (size_t)bh*131072;
  const unsigned short* qlp = qlo_g + (size_t)bh*131072;
  const float* vg = vb + (size_t)bh*T_*128 + sl*16;
  const float* gg = gbuf + (size_t)bh*T_;
  const float* beg = bbuf + (size_t)bh*T_;
  float* og = ob + (size_t)bh*T_*128 + sl*16;

  f32x4 sreg = (f32x4){0.f, 0.f, 0.f, 0.f};
  const int kk0 = wv*16 + v16;
  const int k8 = kk0 >> 3, k7 = kk0 & 7;
  const int kq4 = (quad & 1) * 4;
  const int kr8 = (wv*16 + quad*4) >> 3;

  gld16(&KhiL[0][tid*8],        kh + tid*8);
  gld16(&KhiL[0][4096 + tid*8], kh + 4096 + tid*8);
  gld16(&KloL[0][tid*8],        klp + tid*8);
  gld16(&KloL[0][4096 + tid*8], klp + 4096 + tid*8);

  for (int ch = 0; ch < 16; ++ch) {
    const int t0 = ch * 64;
    const int cur = ch & 1;
    __syncthreads();

    if (ch < 15) {
      const size_t co = (size_t)(t0 + 64) * 128;
      gld16(&KhiL[cur^1][tid*8],        kh + co + tid*8);
      gld16(&KhiL[cur^1][4096 + tid*8], kh + co + 4096 + tid*8);
      gld16(&KloL[cur^1][tid*8],        klp + co + tid*8);
      gld16(&KloL[cur^1][4096 + tid*8], klp + co + 4096 + tid*8);
    }

    float gv = gg[t0 + lane];
    #pragma unroll
    for (int o = 1; o < 64; o <<= 1) {
      float y = __shfl_up(gv, o);
      if (lane >= o) gv += y;
    }
    float bv = beg[t0 + lane];

    const int ar = tb + v16;
    const int arx = ar & 7;
    const size_t tbo = ((size_t)(bh*16 + ch)) * 4096;
    bf16x8 tfh0, tfh1, tfl0, tfl1;
    bf16x8 bfh0, bfh1, bfl0, bfl1;
    bf16x8 qfh[4], qfl[4];
    if (!isQ) {
      int a0 = ar*64 + ((quad ^ arx) << 3);
      int a1 = ar*64 + (((4 + quad) ^ arx) << 3);
      tfh0 = *(const bf16x8*)&Thi_g[tbo + a0];
      tfh1 = *(const bf16x8*)&Thi_g[tbo + a1];
      tfl0 = *(const bf16x8*)&Tlo_g[tbo + a0];
      tfl1 = *(const bf16x8*)&Tlo_g[tbo + a1];
    } else {
      int a0 = ar*64 + ((quad ^ arx) << 3);
      int a1 = ar*64 + (((4 + quad) ^ arx) << 3);
      bfh0 = *(const bf16x8*)&Bhi_g[tbo + a0];
      bfh1 = *(const bf16x8*)&Bhi_g[tbo + a1];
      bfl0 = *(const bf16x8*)&Blo_g[tbo + a0];
      bfl1 = *(const bf16x8*)&Blo_g[tbo + a1];
      const size_t qco = (size_t)t0 * 128;
      #pragma unroll
      for (int ks = 0; ks < 4; ++ks) {
        int ao = ar*128 + (((4*ks + quad) ^ arx) << 3);
        qfh[ks] = *(const bf16x8*)&qh[qco + ao];
        qfl[ks] = *(const bf16x8*)&qlp[qco + ao];
      }
    }

    f32x4 facc = (f32x4){0.f,0.f,0.f,0.f};
    if (ch) {
      f32x4 f2 = (f32x4){0.f,0.f,0.f,0.f};
      #pragma unroll
      for (int ks = 0; ks < 4; ++ks) {
        const int u = 4*ks + quad;
        const int bo = v16*128 + ((u ^ vx) << 3);
        bf16x8 bhi = *(const bf16x8*)&S0h[bo];
        bf16x8 blo = *(const bf16x8*)&S0l[bo];
        bf16x8 ahi, alo;
        if (!isQ) {
          const int ao = ar*128 + ((u ^ arx) << 3);
          ahi = *(const bf16x8*)&KhiL[cur][ao];
          alo = *(const bf16x8*)&KloL[cur][ao];
        } else {
          ahi = qfh[ks]; alo = qfl[ks];
        }
        facc = MFMA16(ahi, bhi, facc);
        f2   = MFMA16(ahi, blo, f2);
        f2   = MFMA16(alo, bhi, f2);
      }
      facc[0] += f2[0]; facc[1] += f2[1]; facc[2] += f2[2]; facc[3] += f2[3];
    }
    const int t4 = tb + quad*4;
    const int wo = v16*64 + ((((t4>>3) ^ vx)) << 3) + (t4 & 7);
    f32x4 qacc = facc;
    if (!isQ) {
      float xr[4];
      #pragma unroll
      for (int r = 0; r < 4; ++r) {
        const int t = t4 + r;
        float be = __shfl(bv, t);
        float ga = __expf(__shfl(gv, t));
        float vvv = vg[(size_t)(t0 + t)*128 + v16];
        xr[r] = fmaf(-be*ga, facc[r], be*vvv);
      }
      ushort4 h4, l4;
      h4.x = f2bf(xr[0]); h4.y = f2bf(xr[1]); h4.z = f2bf(xr[2]); h4.w = f2bf(xr[3]);
      l4.x = f2bf(xr[0]-bfu2f(h4.x)); l4.y = f2bf(xr[1]-bfu2f(h4.y));
      l4.z = f2bf(xr[2]-bfu2f(h4.z)); l4.w = f2bf(xr[3]-bfu2f(h4.w));
      *(ushort4*)&WTh[wo] = h4;
      *(ushort4*)&WTl[wo] = l4;
    }
    __syncthreads();

    if (!isQ) {
      f32x4 wa = (f32x4){0.f,0.f,0.f,0.f};
      f32x4 wb = (f32x4){0.f,0.f,0.f,0.f};
      {
        const int b0 = v16*64 + ((quad ^ vx) << 3);
        const int b1 = v16*64 + (((4 + quad) ^ vx) << 3);
        bf16x8 r0h = *(const bf16x8*)&WTh[b0];
        bf16x8 r0l = *(const bf16x8*)&WTl[b0];
        bf16x8 r1h = *(const bf16x8*)&WTh[b1];
        bf16x8 r1l = *(const bf16x8*)&WTl[b1];
        wa = MFMA16(tfh0, r0h, wa);
        wb = MFMA16(tfh0, r0l, wb);
        wb = MFMA16(tfl0, r0h, wb);
        wa = MFMA16(tfh1, r1h, wa);
        wb = MFMA16(tfh1, r1l, wb);
        wb = MFMA16(tfl1, r1h, wb);
      }
      float Le = __shfl(gv, 63);
      float x0 = wa[0]+wb[0], x1 = wa[1]+wb[1], x2 = wa[2]+wb[2], x3 = wa[3]+wb[3];
      ushort4 h4, l4;
      h4.x = f2bf(x0); h4.y = f2bf(x1); h4.z = f2bf(x2); h4.w = f2bf(x3);
      l4.x = f2bf(x0-bfu2f(h4.x)); l4.y = f2bf(x1-bfu2f(h4.y));
      l4.z = f2bf(x2-bfu2f(h4.z)); l4.w = f2bf(x3-bfu2f(h4.w));
      *(ushort4*)&W2Th[wo] = h4;
      *(ushort4*)&W2Tl[wo] = l4;
      float w30 = x0 * __expf(Le - __shfl(gv, t4+0));
      float w31 = x1 * __expf(Le - __shfl(gv, t4+1));
      float w32 = x2 * __expf(Le - __shfl(gv, t4+2));
      float w33 = x3 * __expf(Le - __shfl(gv, t4+3));
      ushort4 h3, l3;
      h3.x = f2bf(w30); h3.y = f2bf(w31); h3.z = f2bf(w32); h3.w = f2bf(w33);
      l3.x = f2bf(w30-bfu2f(h3.x)); l3.y = f2bf(w31-bfu2f(h3.y));
      l3.z = f2bf(w32-bfu2f(h3.z)); l3.w = f2bf(w33-bfu2f(h3.w));
      *(ushort4*)&W3Th[wo] = h3;
      *(ushort4*)&W3Tl[wo] = l3;
    }
    __syncthreads();

    if (isQ) {
      f32x4 oa = (f32x4){0.f,0.f,0.f,0.f};
      f32x4 ob2 = (f32x4){0.f,0.f,0.f,0.f};
      const int b0 = v16*64 + ((quad ^ vx) << 3);
      const int b1 = v16*64 + (((4 + quad) ^ vx) << 3);
      bf16x8 w0h = *(const bf16x8*)&W2Th[b0];
      bf16x8 w0l = *(const bf16x8*)&W2Tl[b0];
      bf16x8 w1h = *(const bf16x8*)&W2Th[b1];
      bf16x8 w1l = *(const bf16x8*)&W2Tl[b1];
      oa  = MFMA16(bfh0, w0h, oa);
      ob2 = MFMA16(bfh0, w0l, ob2);
      ob2 = MFMA16(bfl0, w0h, ob2);
      oa  = MFMA16(bfh1, w1h, oa);
      ob2 = MFMA16(bfh1, w1l, ob2);
      ob2 = MFMA16(bfl1, w1h, ob2);
      #pragma unroll
      for (int r = 0; r < 4; ++r) {
        const int t = t4 + r;
        float ga = __expf(__shfl(gv, t));
        og[(size_t)(t0 + t)*128 + v16] = fmaf(ga, qacc[r], oa[r] + ob2[r]);
      }
    }

    if (ch != 15) {
      float gC = __expf(__shfl(gv, 63));
      sreg[0] *= gC; sreg[1] *= gC; sreg[2] *= gC; sreg[3] *= gC;
      f32x4 s2 = (f32x4){0.f,0.f,0.f,0.f};
      #pragma unroll
      for (int ks = 0; ks < 2; ++ks) {
        const int u = 4*ks + quad;
        const int tbase = u * 8;
        bf16x8 ahi, alo;
        #pragma unroll
        for (int j = 0; j < 8; ++j) {
          const int ad = (tbase + j)*128 + ((k8 ^ j) << 3) + k7;
          ahi[j] = *(const __bf16*)&KhiL[cur][ad];
          alo[j] = *(const __bf16*)&KloL[cur][ad];
        }
        const int bo = v16*64 + ((u ^ vx) << 3);
        bf16x8 bhi = *(const bf16x8*)&W3Th[bo];
        bf16x8 blo = *(const bf16x8*)&W3Tl[bo];
        sreg = MFMA16(ahi, bhi, sreg);
        s2   = MFMA16(ahi, blo, s2);
        s2   = MFMA16(alo, bhi, s2);
      }
      sreg[0] += s2[0]; sreg[1] += s2[1]; sreg[2] += s2[2]; sreg[3] += s2[3];
      const int so = v16*128 + ((kr8 ^ vx) << 3) + kq4;
      ushort4 h4, l4;
      h4.x = f2bf(sreg[0]); h4.y = f2bf(sreg[1]);
      h4.z = f2bf(sreg[2]); h4.w = f2bf(sreg[3]);
      l4.x = f2bf(sreg[0]-bfu2f(h4.x)); l4.y = f2bf(sreg[1]-bfu2f(h4.y));
      l4.z = f2bf(sreg[2]-bfu2f(h4.z)); l4.w = f2bf(sreg[3]-bfu2f(h4.w));
      *(ushort4*)&S0h[so] = h4;
      *(ushort4*)&S0l[so] = l4;
    }
  }
}

// rmsnorm(o)*norm_w*silu(z) -> bf16 og; z bf16.
// 256 threads = 4 rows/block.
__global__ __launch_bounds__(256) void gnorm_kernel(
    const float* __restrict__ ob, const unsigned short* __restrict__ zbb,
    const float* __restrict__ norm_w, unsigned short* __restrict__ og) {
  const int tid = threadIdx.x;
  const int idx = blockIdx.x * 4 + (tid >> 6);
  const int lane = tid & 63;
  const int t = idx & 1023;
  const int bh = idx >> 10;
  const int b = bh >> 3;
  const int h = bh & 7;
  const float* o = ob + ((size_t)bh*T_ + t)*128;
  float2 ov = *(const float2*)(o + lane*2);
  float ss = fmaf(ov.x, ov.x, ov.y*ov.y);
  #pragma unroll
  for (int m=1; m<64; m<<=1) ss += __shfl_xor(ss, m);
  float inv = rsqrtf(ss*(1.f/128.f) + 1e-6f);
  size_t zoff = ((size_t)(b*T_+t))*1024 + (size_t)h*128 + lane*2;
  ushort2 zv = *(const ushort2*)(zbb + zoff);
  float z0 = bfu2f(zv.x), z1 = bfu2f(zv.y);
  float n0 = norm_w[lane*2], n1 = norm_w[lane*2+1];
  float r0 = ov.x*inv*n0 * z0/(1.f+expf(-z0));
  float r1 = ov.y*inv*n1 * z1/(1.f+expf(-z1));
  ushort2 ot;
  ot.x = f2bf(r0); ot.y = f2bf(r1);
  *(ushort2*)(og + zoff) = ot;
}

extern "C" void kernel_launch(void* const* d_in, const int* in_sizes, int n_in,
                              void* d_out, int out_size, void* d_ws, size_t ws_size,
                              hipStream_t stream) {
  const float* hs     = (const float*)d_in[0];
  const float* qkv_w  = (const float*)d_in[1];
  const float* z_w    = (const float*)d_in[2];
  const float* b_w    = (const float*)d_in[3];
  const float* a_w    = (const float*)d_in[4];
  const float* conv_w = (const float*)d_in[5];
  const float* dt_bias= (const float*)d_in[6];
  const float* A_log  = (const float*)d_in[7];
  const float* norm_w = (const float*)d_in[8];
  const float* out_w  = (const float*)d_in[9];
  float* out = (float*)d_out;

  char* wsp = (char*)d_ws;
  size_t off = 0;
  auto give = [&](size_t bytes)->char*{
    char* p = wsp + off; off += (bytes + 255) & ~(size_t)255; return p;
  };
  char* big    = give((size_t)MROWS*CONV_DIM_*4);            // 48 MB: k/q hi/lo + v
  unsigned short* zbuf = (unsigned short*)give((size_t)MROWS*1024*2);  // 8 MB
  unsigned short* outw_bf = (unsigned short*)give((size_t)HID_*1024*2); // 2 MB
  char* bufA   = give((size_t)32*T_*128*4);                  // 16 MB
  char* bufB   = give((size_t)32*T_*128*4);                  // 16 MB
  char* bufC   = give((size_t)32*T_*128*4);                  // 16 MB
  float* gbuf  = (float*)give((size_t)32*T_*4);
  float* beta  = (float*)give((size_t)32*T_*4);

  // big (48 MB): fused GEMM+conv outputs
  unsigned short* khi = (unsigned short*)big;                     // 8 MB
  unsigned short* klo = khi + (size_t)4*1024*1024;                // 8 MB
  unsigned short* qhi = klo + (size_t)4*1024*1024;                // 8 MB
  unsigned short* qlo = qhi + (size_t)4*1024*1024;                // 8 MB
  float* vdat = (float*)(qlo + (size_t)4*1024*1024);              // 16 MB
  // bufA: wz_bf [0,2MB) -> Blo [2,6MB) -> og [6,10MB); edge [10,12.25MB)
  unsigned short* wz_bf = (unsigned short*)bufA;
  unsigned short* Blo_g = (unsigned short*)bufA + (size_t)1024*1024;
  unsigned short* og    = (unsigned short*)bufA + (size_t)3*1024*1024;
  float* edge           = (float*)(bufA + (size_t)10*1024*1024);  // 2.25 MB
  // bufB: hs_hi/lo [0,16MB) -> Thi [0,4) Tlo [4,8) Bhi [8,12)
  unsigned short* hs_hi = (unsigned short*)bufB;
  unsigned short* hs_lo = hs_hi + (size_t)MROWS*HID_;
  unsigned short* Thi_g = (unsigned short*)bufB;
  unsigned short* Tlo_g = Thi_g + (size_t)512*4096;
  unsigned short* Bhi_g = Tlo_g + (size_t)512*4096;
  // bufC: wc_hi/lo [0,12.6MB) -> ob [0,16MB)
  unsigned short* wc_hi = (unsigned short*)bufC;
  unsigned short* wc_lo = wc_hi + (size_t)CONV_DIM_*HID_;
  float* ob = (float*)bufC;

  convert_weights_kernel<<<dim3(5120), 256, 0, stream>>>(
      qkv_w, z_w, out_w, wc_hi, wc_lo, wz_bf, outw_bf);
  proj_ba_kernel<<<dim3(MROWS), dim3(128), 0, stream>>>(
      hs, b_w, a_w, dt_bias, A_log, gbuf, beta, hs_hi, hs_lo);
  gemm_mfma_kernel<1><<<dim3(1024/128, MROWS/128), 256, 0, stream>>>(
      hs_hi, wz_bf, zbuf, MROWS, 1024, HID_);
  gemm_split_conv_kernel<<<dim3(CONV_DIM_/128, MROWS/128), 256, 0, stream>>>(
      hs_hi, hs_lo, wc_hi, wc_lo, conv_w, qhi, qlo, khi, klo, vdat, edge);
  conv_fix_kernel<<<dim3(32*24), dim3(128), 0, stream>>>(
      edge, conv_w, qhi, qlo, khi, klo, vdat);
  scan_ab_kernel<<<dim3(512), dim3(256), 0, stream>>>(
      qhi, qlo, khi, klo, gbuf, beta, Thi_g, Tlo_g, Bhi_g, Blo_g);
  scan_seq_kernel<<<dim3(256), dim3(512), 0, stream>>>(
      khi, klo, qhi, qlo, vdat, gbuf, beta, Thi_g, Tlo_g, Bhi_g, Blo_g, ob);
  gnorm_kernel<<<dim3(32*T_/4), dim3(256), 0, stream>>>(ob, zbuf, norm_w, og);
  gemm_mfma_kernel<0><<<dim3(1024/128, MROWS/128), 256, 0, stream>>>(og, outw_bf, out, MROWS, 1024, HID_);
}

// Round 13
// 335.845 us; speedup vs baseline: 1.0179x; 1.0179x over previous
//
#include <hip/hip_runtime.h>

#define B_ 4
#define T_ 1024
#define HID_ 1024
#define H_ 8
#define CONV_DIM_ 3072
#define MROWS (B_*T_)

typedef __bf16 bf16x8 __attribute__((ext_vector_type(8)));
typedef float f32x4 __attribute__((ext_vector_type(4)));

#define MFMA16(a,b,c) __builtin_amdgcn_mfma_f32_16x16x32_bf16((a),(b),(c),0,0,0)

static __device__ __forceinline__ unsigned short f2bf(float f) {
  unsigned u = __float_as_uint(f);
  unsigned r = u + 0x7fffu + ((u >> 16) & 1u);   // RNE
  return (unsigned short)(r >> 16);
}
static __device__ __forceinline__ float bfu2f(unsigned short v) {
  return __uint_as_float(((unsigned)v) << 16);
}
static __device__ __forceinline__ float4 recon4(ushort4 h, ushort4 l) {
  float4 r;
  r.x = bfu2f(h.x) + bfu2f(l.x);
  r.y = bfu2f(h.y) + bfu2f(l.y);
  r.z = bfu2f(h.z) + bfu2f(l.z);
  r.w = bfu2f(h.w) + bfu2f(l.w);
  return r;
}

// async global->LDS 16B. LDS dest must be wave-uniform base + lane*16 (m104/m108).
static __device__ __forceinline__ void gld16(void* lds, const void* g) {
  __builtin_amdgcn_global_load_lds(
      (const __attribute__((address_space(1))) unsigned int*)g,
      (__attribute__((address_space(3))) unsigned int*)lds, 16, 0, 0);
}

// Merged weight conversions: qkv_w -> hi/lo split (blocks 0..3071),
// z_w -> bf16 (3072..4095), out_w -> bf16 (4096..5119).
__global__ __launch_bounds__(256) void convert_weights_kernel(
    const float* __restrict__ qkv_w, const float* __restrict__ z_w,
    const float* __restrict__ out_w,
    unsigned short* __restrict__ wc_hi, unsigned short* __restrict__ wc_lo,
    unsigned short* __restrict__ wz_bf, unsigned short* __restrict__ outw_bf) {
  const int bid = blockIdx.x;
  const int tid = threadIdx.x;
  if (bid < 3072) {
    int i = (bid * 256 + tid) * 4;
    float4 v = *(const float4*)(qkv_w + i);
    ushort4 h, l;
    h.x = f2bf(v.x); h.y = f2bf(v.y); h.z = f2bf(v.z); h.w = f2bf(v.w);
    l.x = f2bf(v.x - bfu2f(h.x));
    l.y = f2bf(v.y - bfu2f(h.y));
    l.z = f2bf(v.z - bfu2f(h.z));
    l.w = f2bf(v.w - bfu2f(h.w));
    *(ushort4*)(wc_hi + i) = h;
    *(ushort4*)(wc_lo + i) = l;
  } else {
    const bool isZ = (bid < 4096);
    const float* src = isZ ? z_w : out_w;
    unsigned short* dst = isZ ? wz_bf : outw_bf;
    int i = (((bid - (isZ ? 3072 : 4096)) * 256) + tid) * 4;
    float4 v = *(const float4*)(src + i);
    ushort4 o;
    o.x = f2bf(v.x); o.y = f2bf(v.y); o.z = f2bf(v.z); o.w = f2bf(v.w);
    *(ushort4*)(dst + i) = o;
  }
}

// Single-pass bf16 MFMA GEMM: C[M,N] = A[M,K] * W[N,K]^T. 128x128 tile, BK=32.
template<int OUT_BF16>
__global__ __launch_bounds__(256) void gemm_mfma_kernel(
    const unsigned short* __restrict__ A, const unsigned short* __restrict__ W,
    void* __restrict__ Cv, int M, int N, int K) {
  __shared__ __align__(16) unsigned short lA[128*32];
  __shared__ __align__(16) unsigned short lB[128*32];
  const int tid  = threadIdx.x;
  const int lane = tid & 63;
  const int wv   = tid >> 6;
  const int wm   = (wv >> 1) * 64;
  const int wn   = (wv & 1) * 64;
  const int m16  = lane & 15;
  const int quad = lane >> 4;
  const int bm = blockIdx.y * 128;
  const int bn = blockIdx.x * 128;

  f32x4 acc[4][4];
  #pragma unroll
  for (int i = 0; i < 4; ++i)
    #pragma unroll
    for (int j = 0; j < 4; ++j)
      acc[i][j] = (f32x4){0.f, 0.f, 0.f, 0.f};

  const int r0 = tid >> 2, c0 = tid & 3;
  const int r1 = r0 + 64;
  const int g0 = (c0 ^ (r0 & 3)) * 8;
  const int g1 = (c0 ^ (r1 & 3)) * 8;
  const unsigned short* Ar0 = A + (size_t)(bm + r0) * K + g0;
  const unsigned short* Ar1 = A + (size_t)(bm + r1) * K + g1;
  const unsigned short* Wr0 = W + (size_t)(bn + r0) * K + g0;
  const unsigned short* Wr1 = W + (size_t)(bn + r1) * K + g1;
  unsigned short* sA0 = &lA[(size_t)tid * 8];
  unsigned short* sA1 = &lA[(size_t)(tid + 256) * 8];
  unsigned short* sB0 = &lB[(size_t)tid * 8];
  unsigned short* sB1 = &lB[(size_t)(tid + 256) * 8];

  int offA[4], offB[4];
  #pragma unroll
  for (int i = 0; i < 4; ++i) {
    int ra = wm + i * 16 + m16;
    offA[i] = ra * 32 + (quad ^ (ra & 3)) * 8;
    int rb = wn + i * 16 + m16;
    offB[i] = rb * 32 + (quad ^ (rb & 3)) * 8;
  }

  for (int k0 = 0; k0 < K; k0 += 32) {
    gld16(sA0, Ar0 + k0);
    gld16(sA1, Ar1 + k0);
    gld16(sB0, Wr0 + k0);
    gld16(sB1, Wr1 + k0);
    __syncthreads();
    bf16x8 af[4], bfr[4];
    #pragma unroll
    for (int i = 0; i < 4; ++i) {
      af[i]  = *(const bf16x8*)&lA[offA[i]];
      bfr[i] = *(const bf16x8*)&lB[offB[i]];
    }
    #pragma unroll
    for (int mi = 0; mi < 4; ++mi)
      #pragma unroll
      for (int ni = 0; ni < 4; ++ni)
        acc[mi][ni] = MFMA16(af[mi], bfr[ni], acc[mi][ni]);
    __syncthreads();
  }

  #pragma unroll
  for (int mi = 0; mi < 4; ++mi) {
    #pragma unroll
    for (int r = 0; r < 4; ++r) {
      size_t row = (size_t)(bm + wm + mi * 16 + quad * 4 + r);
      #pragma unroll
      for (int ni = 0; ni < 4; ++ni) {
        int col = bn + wn + ni * 16 + m16;
        float val = acc[mi][ni][r];
        if (OUT_BF16) ((unsigned short*)Cv)[row * N + col] = f2bf(val);
        else          ((float*)Cv)[row * N + col] = val;
      }
    }
  }
}

// Fused: split-precision MFMA GEMM (mixed = hs.qkv_w^T, 3 products) + causal
// depthwise conv (K=4) epilogue, PLUS merged z-projection (z = hs.z_w^T,
// single product, bf16 out) on blocks x>=24 — kills the separate z-gemm
// launch; z blocks pack into the same dispatch's CU bubbles.
// NOTE (round-11 lesson): the Alo.Whi term is REQUIRED — dropping it gave
// absmax 0.18 (the scan recurrence amplifies q/k operand error ~100x).
// Epilogue: two 64-row half-tiles through [64][132] fp32 LDS (35328B total).
__global__ __launch_bounds__(256) void gemm_split_conv_kernel(
    const unsigned short* __restrict__ Ahi, const unsigned short* __restrict__ Alo,
    const unsigned short* __restrict__ Whi, const unsigned short* __restrict__ Wlo,
    const unsigned short* __restrict__ Wz,
    const float* __restrict__ conv_w,
    unsigned short* __restrict__ qhi, unsigned short* __restrict__ qlo,
    unsigned short* __restrict__ khi, unsigned short* __restrict__ klo,
    float* __restrict__ vb, float* __restrict__ edge,
    unsigned short* __restrict__ zbuf) {
  // LDS union: 4 staging tiles (32768B) during K-loop; epilogue: smX2 [64][132]
  // fp32 (33792B) + carry [3][128] fp32 (1536B) = 35328B total.
  __shared__ __align__(16) unsigned char ldsraw[64*132*4 + 3*128*4];
  unsigned short* lAh = (unsigned short*)ldsraw;
  unsigned short* lAl = lAh + 128*32;
  unsigned short* lBh = lAl + 128*32;
  unsigned short* lBl = lBh + 128*32;
  float* smX2  = (float*)ldsraw;
  float* carry = (float*)(ldsraw + 64*132*4);

  const int tid  = threadIdx.x;
  const int lane = tid & 63;
  const int wv   = tid >> 6;
  const int wm   = (wv >> 1) * 64;
  const int wn   = (wv & 1) * 64;
  const int m16  = lane & 15;
  const int quad = lane >> 4;
  const int bm = blockIdx.y * 128;

  f32x4 acc[4][4];
  #pragma unroll
  for (int i = 0; i < 4; ++i)
    #pragma unroll
    for (int j = 0; j < 4; ++j)
      acc[i][j] = (f32x4){0.f, 0.f, 0.f, 0.f};

  const int r0 = tid >> 2, c0 = tid & 3;
  const int r1 = r0 + 64;
  const int g0 = (c0 ^ (r0 & 3)) * 8;
  const int g1 = (c0 ^ (r1 & 3)) * 8;
  const size_t oA0 = (size_t)(bm + r0) * 1024 + g0;
  const size_t oA1 = (size_t)(bm + r1) * 1024 + g1;
  const int s0 = tid * 8, s1 = (tid + 256) * 8;

  int offA[4], offB[4];
  #pragma unroll
  for (int i = 0; i < 4; ++i) {
    int ra = wm + i * 16 + m16;
    offA[i] = ra * 32 + (quad ^ (ra & 3)) * 8;
    int rb = wn + i * 16 + m16;
    offB[i] = rb * 32 + (quad ^ (rb & 3)) * 8;
  }

  // ---- z path (blocks x>=24): z = hs_hi . z_w^T, single product, bf16 out.
  // Block-uniform branch; byte-identical math to the old gemm_mfma<1> launch.
  if (blockIdx.x >= 24) {
    const int bn = (blockIdx.x - 24) * 128;
    const size_t oBz0 = (size_t)(bn + r0) * 1024 + g0;
    const size_t oBz1 = (size_t)(bn + r1) * 1024 + g1;
    for (int k0 = 0; k0 < 1024; k0 += 32) {
      gld16(&lAh[s0], Ahi + oA0 + k0);
      gld16(&lAh[s1], Ahi + oA1 + k0);
      gld16(&lBh[s0], Wz + oBz0 + k0);
      gld16(&lBh[s1], Wz + oBz1 + k0);
      __syncthreads();
      bf16x8 af[4], bfr[4];
      #pragma unroll
      for (int i = 0; i < 4; ++i) {
        af[i]  = *(const bf16x8*)&lAh[offA[i]];
        bfr[i] = *(const bf16x8*)&lBh[offB[i]];
      }
      #pragma unroll
      for (int mi = 0; mi < 4; ++mi)
        #pragma unroll
        for (int ni = 0; ni < 4; ++ni)
          acc[mi][ni] = MFMA16(af[mi], bfr[ni], acc[mi][ni]);
      __syncthreads();
    }
    #pragma unroll
    for (int mi = 0; mi < 4; ++mi) {
      #pragma unroll
      for (int r = 0; r < 4; ++r) {
        size_t row = (size_t)(bm + wm + mi * 16 + quad * 4 + r);
        #pragma unroll
        for (int ni = 0; ni < 4; ++ni)
          zbuf[row * 1024 + bn + wn + ni * 16 + m16] = f2bf(acc[mi][ni][r]);
      }
    }
    return;
  }

  // ---- qkv path (blocks x<24): unchanged from round 12
  const int bn = blockIdx.x * 128;
  const size_t oB0 = (size_t)(bn + r0) * 1024 + g0;
  const size_t oB1 = (size_t)(bn + r1) * 1024 + g1;

  for (int k0 = 0; k0 < 1024; k0 += 32) {
    gld16(&lAh[s0], Ahi + oA0 + k0);
    gld16(&lAh[s1], Ahi + oA1 + k0);
    gld16(&lAl[s0], Alo + oA0 + k0);
    gld16(&lAl[s1], Alo + oA1 + k0);
    gld16(&lBh[s0], Whi + oB0 + k0);
    gld16(&lBh[s1], Whi + oB1 + k0);
    gld16(&lBl[s0], Wlo + oB0 + k0);
    gld16(&lBl[s1], Wlo + oB1 + k0);
    __syncthreads();
    bf16x8 afh[4], bfh[4];
    #pragma unroll
    for (int i = 0; i < 4; ++i) {
      afh[i] = *(const bf16x8*)&lAh[offA[i]];
      bfh[i] = *(const bf16x8*)&lBh[offB[i]];
    }
    #pragma unroll
    for (int mi = 0; mi < 4; ++mi)
      #pragma unroll
      for (int ni = 0; ni < 4; ++ni)
        acc[mi][ni] = MFMA16(afh[mi], bfh[ni], acc[mi][ni]);
    {
      bf16x8 bfl[4];
      #pragma unroll
      for (int i = 0; i < 4; ++i) bfl[i] = *(const bf16x8*)&lBl[offB[i]];
      #pragma unroll
      for (int mi = 0; mi < 4; ++mi)
        #pragma unroll
        for (int ni = 0; ni < 4; ++ni)
          acc[mi][ni] = MFMA16(afh[mi], bfl[ni], acc[mi][ni]);
    }
    {
      bf16x8 afl[4];
      #pragma unroll
      for (int i = 0; i < 4; ++i) afl[i] = *(const bf16x8*)&lAl[offA[i]];
      #pragma unroll
      for (int mi = 0; mi < 4; ++mi)
        #pragma unroll
        for (int ni = 0; ni < 4; ++ni)
          acc[mi][ni] = MFMA16(afl[mi], bfh[ni], acc[mi][ni]);
    }
    __syncthreads();   // last iter: all staging reads done -> smX2 alias safe
  }

  // ---- epilogue: two 64-row half-tiles
  const int bi = blockIdx.y;
  const int c  = tid & 127;
  const int rh = tid >> 7;
  const int cg = bn + c;
  const int part = cg >> 10;         // block-uniform
  const int hh = (cg & 1023) >> 7;   // block-uniform
  const int b = bm >> 10;
  const int tloc0 = bm & 1023;
  float4 w4 = *(const float4*)(conv_w + cg * 4);
  size_t rowb = ((size_t)(b * H_ + hh)) * T_;
  unsigned short* dh = (part == 0) ? qhi : khi;
  unsigned short* dl = (part == 0) ? qlo : klo;

  #pragma unroll
  for (int half = 0; half < 2; ++half) {
    if (half == 1) __syncthreads();   // half-0 conv reads + carry save done
    // write this half's acc rows into smX2 (local rows 0..63)
    if ((wv >> 1) == half) {
      #pragma unroll
      for (int mi = 0; mi < 4; ++mi)
        #pragma unroll
        for (int r = 0; r < 4; ++r) {
          int row = mi * 16 + quad * 4 + r;
          #pragma unroll
          for (int ni = 0; ni < 4; ++ni)
            smX2[row * 132 + wn + ni * 16 + m16] = acc[mi][ni][r];
        }
    }
    __syncthreads();
    // edge spill + (half 0) carry save — 384 items via e*256+tid (256 threads)
    if (half == 0) {
      #pragma unroll
      for (int e = 0; e < 2; ++e) {
        int idx = e * 256 + tid;
        int r = idx >> 7, cc = idx & 127;
        if (r < 3) {
          edge[((size_t)bi*6 + 3 + r)*3072 + bn + cc] = smX2[r*132 + cc];
          carry[r*128 + cc] = smX2[(61+r)*132 + cc];
        }
      }
    } else {
      if (bi < 31) {
        #pragma unroll
        for (int e = 0; e < 2; ++e) {
          int idx = e * 256 + tid;
          int r = idx >> 7, cc = idx & 127;
          if (r < 3)
            edge[((size_t)(bi+1)*6 + r)*3072 + bn + cc] = smX2[(61+r)*132 + cc];
        }
      }
    }
    // conv: 2 threads/col, 32 t-steps each
    {
      const int tb0 = rh * 32;
      float x0, x1, x2;
      if (tb0 >= 3) {
        x0 = smX2[(tb0-3)*132 + c];
        x1 = smX2[(tb0-2)*132 + c];
        x2 = smX2[(tb0-1)*132 + c];
      } else {  // tb0 == 0
        if (half == 0) { x0 = 0.f; x1 = 0.f; x2 = 0.f; }
        else { x0 = carry[0*128 + c]; x1 = carry[1*128 + c]; x2 = carry[2*128 + c]; }
      }
      for (int tt = 0; tt < 32; ++tt) {
        const int t = tb0 + tt;
        float x3 = smX2[t*132 + c];
        float s = fmaf(w4.x, x0, fmaf(w4.y, x1, fmaf(w4.z, x2, w4.w * x3)));
        x0 = x1; x1 = x2; x2 = x3;
        const int tg = tloc0 + half*64 + t;
        if (part == 2) {
          vb[(rowb + tg) * 128 + c] = s;
        } else {
          int sw = (((c >> 3) ^ (tg & 7)) << 3) + (c & 7);
          unsigned short hv = f2bf(s);
          dh[(rowb + tg) * 128 + sw] = hv;
          dl[(rowb + tg) * 128 + sw] = f2bf(s - bfu2f(hv));
        }
      }
    }
  }
}

// Boundary fixup (trivial): 6 mixed rows come straight from the edge buffer.
__global__ __launch_bounds__(128) void conv_fix_kernel(
    const float* __restrict__ edge, const float* __restrict__ conv_w,
    unsigned short* __restrict__ qhi, unsigned short* __restrict__ qlo,
    unsigned short* __restrict__ khi, unsigned short* __restrict__ klo,
    float* __restrict__ vb) {
  const int bi = blockIdx.x / 24;
  const int cb = blockIdx.x % 24;
  const int bm = bi * 128, n0 = cb * 128;
  const int b = bm >> 10, tloc = bm & 1023;
  const int c = threadIdx.x;
  const int cg = n0 + c;
  float m[6];
  #pragma unroll
  for (int j = 0; j < 6; ++j)
    m[j] = edge[((size_t)bi*6 + j)*3072 + cg];
  if (tloc == 0) { m[0] = 0.f; m[1] = 0.f; m[2] = 0.f; }
  const int part = cg >> 10;
  const int hh = (cg & 1023) >> 7;
  float4 w4 = *(const float4*)(conv_w + cg * 4);
  size_t rowb = ((size_t)(b * H_ + hh)) * T_;
  unsigned short* dh = (part == 0) ? qhi : khi;
  unsigned short* dl = (part == 0) ? qlo : klo;
  #pragma unroll
  for (int jo = 0; jo < 3; ++jo) {
    float s = fmaf(w4.x, m[jo], fmaf(w4.y, m[jo+1],
              fmaf(w4.z, m[jo+2], w4.w * m[jo+3])));
    const int tg = tloc + jo;
    if (part == 2) {
      vb[(rowb + tg) * 128 + c] = s;
    } else {
      int sw = (((c >> 3) ^ (tg & 7)) << 3) + (c & 7);
      unsigned short hv = f2bf(s);
      dh[(rowb + tg) * 128 + sw] = hv;
      dl[(rowb + tg) * 128 + sw] = f2bf(s - bfu2f(hv));
    }
  }
}

// bb/aa projections fused with beta / g=log(alpha). Reads fp32 hs (exact).
// ALSO emits hs as bf16 hi/lo via a separate COALESCED all-thread pass.
__global__ __launch_bounds__(128) void proj_ba_kernel(
    const float* __restrict__ hs, const float* __restrict__ b_w, const float* __restrict__ a_w,
    const float* __restrict__ dt_bias, const float* __restrict__ A_log,
    float* __restrict__ gout, float* __restrict__ beta,
    unsigned short* __restrict__ hs_hi, unsigned short* __restrict__ hs_lo) {
  const int bt = blockIdx.x;
  const int b = bt >> 10;
  const int t = bt & 1023;
  const int tid = threadIdx.x;
  const int grp = tid >> 3;
  const int l8 = tid & 7;
  const int h = grp & 7;
  const bool isA = grp >= 8;
  const float* w = (isA ? a_w : b_w) + (size_t)h * HID_;
  const float* x = hs + (size_t)bt * HID_;
  // coalesced hs -> bf16 hi/lo emit: 128 threads x 8 elems
  {
    const int e = tid * 8;
    float4 xv0 = *(const float4*)(x + e);
    float4 xv1 = *(const float4*)(x + e + 4);
    ushort4 h0, l0, h1, l1;
    h0.x = f2bf(xv0.x); h0.y = f2bf(xv0.y); h0.z = f2bf(xv0.z); h0.w = f2bf(xv0.w);
    l0.x = f2bf(xv0.x - bfu2f(h0.x)); l0.y = f2bf(xv0.y - bfu2f(h0.y));
    l0.z = f2bf(xv0.z - bfu2f(h0.z)); l0.w = f2bf(xv0.w - bfu2f(h0.w));
    h1.x = f2bf(xv1.x); h1.y = f2bf(xv1.y); h1.z = f2bf(xv1.z); h1.w = f2bf(xv1.w);
    l1.x = f2bf(xv1.x - bfu2f(h1.x)); l1.y = f2bf(xv1.y - bfu2f(h1.y));
    l1.z = f2bf(xv1.z - bfu2f(h1.z)); l1.w = f2bf(xv1.w - bfu2f(h1.w));
    unsigned short* hho = hs_hi + (size_t)bt * HID_ + e;
    unsigned short* hlo = hs_lo + (size_t)bt * HID_ + e;
    *(ushort4*)hho = h0;       *(ushort4*)hlo = l0;
    *(ushort4*)(hho + 4) = h1; *(ushort4*)(hlo + 4) = l1;
  }
  float s = 0.f;
  for (int e = l8*4; e < HID_; e += 32){
    float4 xv = *(const float4*)(x + e);
    float4 wv = *(const float4*)(w + e);
    s = fmaf(xv.x, wv.x, s);
    s = fmaf(xv.y, wv.y, s);
    s = fmaf(xv.z, wv.z, s);
    s = fmaf(xv.w, wv.w, s);
  }
  s += __shfl_xor(s,1); s += __shfl_xor(s,2); s += __shfl_xor(s,4);
  if (l8 == 0) {
    size_t o = ((size_t)(b*H_ + h))*T_ + t;
    if (!isA) {
      beta[o] = 1.f/(1.f+expf(-s));
    } else {
      float xx = s + dt_bias[h];
      float sp = fmaxf(xx,0.f) + log1pf(expf(-fabsf(xx)));   // softplus
      gout[o] = -expf(A_log[h]) * sp;                        // g = log(alpha)
    }
  }
}

// Parallel precompute: 512 blocks = (bh, chunk). MFMA version.
// T = (I+A)^-1 (unit lower), B = incl-lower decayed QK^T.
// K.K^T and Q.K^T on matrix cores (hi/lo 3-chain split), fragments loaded
// directly from the pre-swizzled global buffers. Upper-triangle tiles
// written as ZEROS. Inversion chain unchanged.
__global__ __launch_bounds__(256) void scan_ab_kernel(
    const unsigned short* __restrict__ qhi_g, const unsigned short* __restrict__ qlo_g,
    const unsigned short* __restrict__ khi_g, const unsigned short* __restrict__ klo_g,
    const float* __restrict__ gbuf, const float* __restrict__ bbuf,
    unsigned short* __restrict__ Thi_g, unsigned short* __restrict__ Tlo_g,
    unsigned short* __restrict__ Bhi_g, unsigned short* __restrict__ Blo_g) {
  const int blk = blockIdx.x;
  const int bh = blk >> 4;
  const int ch = blk & 15;
  const int t0 = ch * 64;
  const int tid = threadIdx.x;
  const int wvb = tid >> 6;          // wave = output row-block
  const int lane = tid & 63;
  const int v16 = lane & 15;
  const int quad = lane >> 4;
  __shared__ float sAA[64][68];
  __shared__ float lL[64];
  __shared__ float bL[64];
  unsigned short* Tho = Thi_g + (size_t)blk*4096;
  unsigned short* Tlo = Tlo_g + (size_t)blk*4096;
  unsigned short* Bho = Bhi_g + (size_t)blk*4096;
  unsigned short* Blo = Blo_g + (size_t)blk*4096;
  const unsigned short* kh  = khi_g + (size_t)bh*131072 + (size_t)t0*128;
  const unsigned short* klp = klo_g + (size_t)bh*131072 + (size_t)t0*128;
  const unsigned short* qh  = qhi_g + (size_t)bh*131072 + (size_t)t0*128;
  const unsigned short* qlp = qlo_g + (size_t)bh*131072 + (size_t)t0*128;

  if (tid < 64) {
    float x = gbuf[(size_t)bh*T_ + t0 + tid];
    #pragma unroll
    for (int o = 1; o < 64; o <<= 1) {
      float y = __shfl_up(x, o);
      if (tid >= o) x += y;
    }
    lL[tid] = x;
    bL[tid] = bbuf[(size_t)bh*T_ + t0 + tid];
  }

  const int ar = wvb*16 + v16;
  const int arx = ar & 7;
  bf16x8 kAh[4], kAl[4], qAh[4], qAl[4];
  #pragma unroll
  for (int ks = 0; ks < 4; ++ks) {
    const int u = 4*ks + quad;
    const int ao = ar*128 + ((u ^ arx) << 3);
    kAh[ks] = *(const bf16x8*)&kh[ao];
    kAl[ks] = *(const bf16x8*)&klp[ao];
    qAh[ks] = *(const bf16x8*)&qh[ao];
    qAl[ks] = *(const bf16x8*)&qlp[ao];
  }
  __syncthreads();   // lL/bL ready

  const int i0 = wvb*16 + quad*4;
  float biv[4], liv[4];
  #pragma unroll
  for (int r = 0; r < 4; ++r) { biv[r] = bL[i0+r]; liv[r] = lL[i0+r]; }

  #pragma unroll
  for (int cb = 0; cb < 4; ++cb) {
    const int j = cb*16 + v16;
    if (cb <= wvb) {
      const int rb = cb*16 + v16;
      const int rbx = rb & 7;
      f32x4 a1 = (f32x4){0.f,0.f,0.f,0.f}, a2 = (f32x4){0.f,0.f,0.f,0.f};
      f32x4 q1 = (f32x4){0.f,0.f,0.f,0.f}, q2 = (f32x4){0.f,0.f,0.f,0.f};
      #pragma unroll
      for (int ks = 0; ks < 4; ++ks) {
        const int u = 4*ks + quad;
        const int bo = rb*128 + ((u ^ rbx) << 3);
        bf16x8 bhv = *(const bf16x8*)&kh[bo];
        bf16x8 blv = *(const bf16x8*)&klp[bo];
        a1 = MFMA16(kAh[ks], bhv, a1);
        a2 = MFMA16(kAh[ks], blv, a2);
        a2 = MFMA16(kAl[ks], bhv, a2);
        q1 = MFMA16(qAh[ks], bhv, q1);
        q2 = MFMA16(qAh[ks], blv, q2);
        q2 = MFMA16(qAl[ks], bhv, q2);
      }
      float lj = lL[j];
      #pragma unroll
      for (int r = 0; r < 4; ++r) {
        const int i = i0 + r;
        float av = a1[r] + a2[r];
        float qv = q1[r] + q2[r];
        sAA[i][j] = (j < i) ? biv[r] * __expf(liv[r] - lj) * av : 0.f;
        float xq = (j <= i) ? __expf(liv[r] - lj) * qv : 0.f;
        unsigned short hv = f2bf(xq);
        int sidx = i*64 + (((j>>3) ^ (i&7)) << 3) + (j&7);
        Bho[sidx] = hv;
        Blo[sidx] = f2bf(xq - bfu2f(hv));
      }
    } else {
      #pragma unroll
      for (int r = 0; r < 4; ++r) {
        const int i = i0 + r;
        sAA[i][j] = 0.f;
        int sidx = i*64 + (((j>>3) ^ (i&7)) << 3) + (j&7);
        Bho[sidx] = 0;
        Blo[sidx] = 0;
      }
    }
  }
  __syncthreads();

  // invert (I+A): 4 waves x 16 cols, rows rr+4m per thread; wave-local chain
  {
    const int w = tid >> 6;
    const int ln = tid & 63;
    const int colc = w*16 + (ln & 15);
    const int rr = ln >> 4;
    float rh[16];
    #pragma unroll
    for (int m=0;m<16;++m) rh[m] = (rr + 4*m == colc) ? 1.f : 0.f;
    for (int j = 0; j < 63; ++j) {
      int src = ((j & 3) << 4) | (ln & 15);
      float wj = __shfl(rh[j >> 2], src);
      #pragma unroll
      for (int m=0;m<16;++m)
        rh[m] = fmaf(-sAA[rr + 4*m][j], wj, rh[m]);
    }
    #pragma unroll
    for (int m=0;m<16;++m) {
      int i2 = rr + 4*m;
      float x = rh[m];
      unsigned short hv = f2bf(x);
      int sidx = i2*64 + (((colc>>3) ^ (i2&7)) << 3) + (colc&7);
      Tho[sidx] = hv;
      Tlo[sidx] = f2bf(x - bfu2f(hv));
    }
  }
}

// Sequential chunked scan, 512 threads (8 waves), UT-transform, all-MFMA phases.
// XCD-aware block decode: bh = bid&31, sl = bid>>5.
__global__ __launch_bounds__(512) void scan_seq_kernel(
    const unsigned short* __restrict__ khi_g, const unsigned short* __restrict__ klo_g,
    const unsigned short* __restrict__ qhi_g, const unsigned short* __restrict__ qlo_g,
    const float* __restrict__ vb,
    const float* __restrict__ gbuf, const float* __restrict__ bbuf,
    const unsigned short* __restrict__ Thi_g, const unsigned short* __restrict__ Tlo_g,
    const unsigned short* __restrict__ Bhi_g, const unsigned short* __restrict__ Blo_g,
    float* __restrict__ ob) {
  const int bh = blockIdx.x & 31;
  const int sl = blockIdx.x >> 5;
  const int tid = threadIdx.x;
  const int wv = tid >> 6;
  const int lane = tid & 63;
  const int v16 = lane & 15;
  const int quad = lane >> 4;
  const int tb = (wv & 3) * 16;
  const bool isQ = (wv >= 4);
  const int vx = v16 & 7;

  __shared__ __align__(16) unsigned short KhiL[2][64*128];
  __shared__ __align__(16) unsigned short KloL[2][64*128];
  __shared__ __align__(16) unsigned short WTh[16*64],  WTl[16*64];
  __shared__ __align__(16) unsigned short W2Th[16*64], W2Tl[16*64];
  __shared__ __align__(16) unsigned short W3Th[16*64], W3Tl[16*64];
  __shared__ __align__(16) unsigned short S0h[16*128], S0l[16*128];

  const unsigned short* kh  = khi_g + (size_t)bh*131072;
  const unsigned short* klp = klo_g + (size_t)bh*131072;
  const unsigned short* qh  = qhi_g + (size_t)bh*131072;
  const unsigned short* qlp = qlo_g + (size_t)bh*131072;
  const float* vg = vb + (size_t)bh*T_*128 + sl*16;
  const float* gg = gbuf + (size_t)bh*T_;
  const float* beg = bbuf + (size_t)bh*T_;
  float* og = ob + (size_t)bh*T_*128 + sl*16;

  f32x4 sreg = (f32x4){0.f, 0.f, 0.f, 0.f};
  const int kk0 = wv*16 + v16;
  const int k8 = kk0 >> 3, k7 = kk0 & 7;
  const int kq4 = (quad & 1) * 4;
  const int kr8 = (wv*16 + quad*4) >> 3;

  gld16(&KhiL[0][tid*8],        kh + tid*8);
  gld16(&KhiL[0][4096 + tid*8], kh + 4096 + tid*8);
  gld16(&KloL[0][tid*8],        klp + tid*8);
  gld16(&KloL[0][4096 + tid*8], klp + 4096 + tid*8);

  for (int ch = 0; ch < 16; ++ch) {
    const int t0 = ch * 64;
    const int cur = ch & 1;
    __syncthreads();

    if (ch < 15) {
      const size_t co = (size_t)(t0 + 64) * 128;
      gld16(&KhiL[cur^1][tid*8],        kh + co + tid*8);
      gld16(&KhiL[cur^1][4096 + tid*8], kh + co + 4096 + tid*8);
      gld16(&KloL[cur^1][tid*8],        klp + co + tid*8);
      gld16(&KloL[cur^1][4096 + tid*8], klp + co + 4096 + tid*8);
    }

    float gv = gg[t0 + lane];
    #pragma unroll
    for (int o = 1; o < 64; o <<= 1) {
      float y = __shfl_up(gv, o);
      if (lane >= o) gv += y;
    }
    float bv = beg[t0 + lane];

    const int ar = tb + v16;
    const int arx = ar & 7;
    const size_t tbo = ((size_t)(bh*16 + ch)) * 4096;
    bf16x8 tfh0, tfh1, tfl0, tfl1;
    bf16x8 bfh0, bfh1, bfl0, bfl1;
    bf16x8 qfh[4], qfl[4];
    if (!isQ) {
      int a0 = ar*64 + ((quad ^ arx) << 3);
      int a1 = ar*64 + (((4 + quad) ^ arx) << 3);
      tfh0 = *(const bf16x8*)&Thi_g[tbo + a0];
      tfh1 = *(const bf16x8*)&Thi_g[tbo + a1];
      tfl0 = *(const bf16x8*)&Tlo_g[tbo + a0];
      tfl1 = *(const bf16x8*)&Tlo_g[tbo + a1];
    } else {
      int a0 = ar*64 + ((quad ^ arx) << 3);
      int a1 = ar*64 + (((4 + quad) ^ arx) << 3);
      bfh0 = *(const bf16x8*)&Bhi_g[tbo + a0];
      bfh1 = *(const bf16x8*)&Bhi_g[tbo + a1];
      bfl0 = *(const bf16x8*)&Blo_g[tbo + a0];
      bfl1 = *(const bf16x8*)&Blo_g[tbo + a1];
      const size_t qco = (size_t)t0 * 128;
      #pragma unroll
      for (int ks = 0; ks < 4; ++ks) {
        int ao = ar*128 + (((4*ks + quad) ^ arx) << 3);
        qfh[ks] = *(const bf16x8*)&qh[qco + ao];
        qfl[ks] = *(const bf16x8*)&qlp[qco + ao];
      }
    }

    f32x4 facc = (f32x4){0.f,0.f,0.f,0.f};
    if (ch) {
      f32x4 f2 = (f32x4){0.f,0.f,0.f,0.f};
      #pragma unroll
      for (int ks = 0; ks < 4; ++ks) {
        const int u = 4*ks + quad;
        const int bo = v16*128 + ((u ^ vx) << 3);
        bf16x8 bhi = *(const bf16x8*)&S0h[bo];
        bf16x8 blo = *(const bf16x8*)&S0l[bo];
        bf16x8 ahi, alo;
        if (!isQ) {
          const int ao = ar*128 + ((u ^ arx) << 3);
          ahi = *(const bf16x8*)&KhiL[cur][ao];
          alo = *(const bf16x8*)&KloL[cur][ao];
        } else {
          ahi = qfh[ks]; alo = qfl[ks];
        }
        facc = MFMA16(ahi, bhi, facc);
        f2   = MFMA16(ahi, blo, f2);
        f2   = MFMA16(alo, bhi, f2);
      }
      facc[0] += f2[0]; facc[1] += f2[1]; facc[2] += f2[2]; facc[3] += f2[3];
    }
    const int t4 = tb + quad*4;
    const int wo = v16*64 + ((((t4>>3) ^ vx)) << 3) + (t4 & 7);
    f32x4 qacc = facc;
    if (!isQ) {
      float xr[4];
      #pragma unroll
      for (int r = 0; r < 4; ++r) {
        const int t = t4 + r;
        float be = __shfl(bv, t);
        float ga = __expf(__shfl(gv, t));
        float vvv = vg[(size_t)(t0 + t)*128 + v16];
        xr[r] = fmaf(-be*ga, facc[r], be*vvv);
      }
      ushort4 h4, l4;
      h4.x = f2bf(xr[0]); h4.y = f2bf(xr[1]); h4.z = f2bf(xr[2]); h4.w = f2bf(xr[3]);
      l4.x = f2bf(xr[0]-bfu2f(h4.x)); l4.y = f2bf(xr[1]-bfu2f(h4.y));
      l4.z = f2bf(xr[2]-bfu2f(h4.z)); l4.w = f2bf(xr[3]-bfu2f(h4.w));
      *(ushort4*)&WTh[wo] = h4;
      *(ushort4*)&WTl[wo] = l4;
    }
    __syncthreads();

    if (!isQ) {
      f32x4 wa = (f32x4){0.f,0.f,0.f,0.f};
      f32x4 wb = (f32x4){0.f,0.f,0.f,0.f};
      {
        const int b0 = v16*64 + ((quad ^ vx) << 3);
        const int b1 = v16*64 + (((4 + quad) ^ vx) << 3);
        bf16x8 r0h = *(const bf16x8*)&WTh[b0];
        bf16x8 r0l = *(const bf16x8*)&WTl[b0];
        bf16x8 r1h = *(const bf16x8*)&WTh[b1];
        bf16x8 r1l = *(const bf16x8*)&WTl[b1];
        wa = MFMA16(tfh0, r0h, wa);
        wb = MFMA16(tfh0, r0l, wb);
        wb = MFMA16(tfl0, r0h, wb);
        wa = MFMA16(tfh1, r1h, wa);
        wb = MFMA16(tfh1, r1l, wb);
        wb = MFMA16(tfl1, r1h, wb);
      }
      float Le = __shfl(gv, 63);
      float x0 = wa[0]+wb[0], x1 = wa[1]+wb[1], x2 = wa[2]+wb[2], x3 = wa[3]+wb[3];
      ushort4 h4, l4;
      h4.x = f2bf(x0); h4.y = f2bf(x1); h4.z = f2bf(x2); h4.w = f2bf(x3);
      l4.x = f2bf(x0-bfu2f(h4.x)); l4.y = f2bf(x1-bfu2f(h4.y));
      l4.z = f2bf(x2-bfu2f(h4.z)); l4.w = f2bf(x3-bfu2f(h4.w));
      *(ushort4*)&W2Th[wo] = h4;
      *(ushort4*)&W2Tl[wo] = l4;
      float w30 = x0 * __expf(Le - __shfl(gv, t4+0));
      float w31 = x1 * __expf(Le - __shfl(gv, t4+1));
      float w32 = x2 * __expf(Le - __shfl(gv, t4+2));
      float w33 = x3 * __expf(Le - __shfl(gv, t4+3));
      ushort4 h3, l3;
      h3.x = f2bf(w30); h3.y = f2bf(w31); h3.z = f2bf(w32); h3.w = f2bf(w33);
      l3.x = f2bf(w30-bfu2f(h3.x)); l3.y = f2bf(w31-bfu2f(h3.y));
      l3.z = f2bf(w32-bfu2f(h3.z)); l3.w = f2bf(w33-bfu2f(h3.w));
      *(ushort4*)&W3Th[wo] = h3;
      *(ushort4*)&W3Tl[wo] = l3;
    }
    __syncthreads();

    if (isQ) {
      f32x4 oa = (f32x4){0.f,0.f,0.f,0.f};
      f32x4 ob2 = (f32x4){0.f,0.f,0.f,0.f};
      const int b0 = v16*64 + ((quad ^ vx) << 3);
      const int b1 = v16*64 + (((4 + quad) ^ vx) << 3);
      bf16x8 w0h = *(const bf16x8*)&W2Th[b0];
      bf16x8 w0l = *(const bf16x8*)&W2Tl[b0];
      bf16x8 w1h = *(const bf16x8*)&W2Th[b1];
      bf16x8 w1l = *(const bf16x8*)&W2Tl[b1];
      oa  = MFMA16(bfh0, w0h, oa);
      ob2 = MFMA16(bfh0, w0l, ob2);
      ob2 = MFMA16(bfl0, w0h, ob2);
      oa  = MFMA16(bfh1, w1h, oa);
      ob2 = MFMA16(bfh1, w1l, ob2);
      ob2 = MFMA16(bfl1, w1h, ob2);
      #pragma unroll
      for (int r = 0; r < 4; ++r) {
        const int t = t4 + r;
        float ga = __expf(__shfl(gv, t));
        og[(size_t)(t0 + t)*128 + v16] = fmaf(ga, qacc[r], oa[r] + ob2[r]);
      }
    }

    if (ch != 15) {
      float gC = __expf(__shfl(gv, 63));
      sreg[0] *= gC; sreg[1] *= gC; sreg[2] *= gC; sreg[3] *= gC;
      f32x4 s2 = (f32x4){0.f,0.f,0.f,0.f};
      #pragma unroll
      for (int ks = 0; ks < 2; ++ks) {
        const int u = 4*ks + quad;
        const int tbase = u * 8;
        bf16x8 ahi, alo;
        #pragma unroll
        for (int j = 0; j < 8; ++j) {
          const int ad = (tbase + j)*128 + ((k8 ^ j) << 3) + k7;
          ahi[j] = *(const __bf16*)&KhiL[cur][ad];
          alo[j] = *(const __bf16*)&KloL[cur][ad];
        }
        const int bo = v16*64 + ((u ^ vx) << 3);
        bf16x8 bhi = *(const bf16x8*)&W3Th[bo];
        bf16x8 blo = *(const bf16x8*)&W3Tl[bo];
        sreg = MFMA16(ahi, bhi, sreg);
        s2   = MFMA16(ahi, blo, s2);
        s2   = MFMA16(alo, bhi, s2);
      }
      sreg[0] += s2[0]; sreg[1] += s2[1]; sreg[2] += s2[2]; sreg[3] += s2[3];
      const int so = v16*128 + ((kr8 ^ vx) << 3) + kq4;
      ushort4 h4, l4;
      h4.x = f2bf(sreg[0]); h4.y = f2bf(sreg[1]);
      h4.z = f2bf(sreg[2]); h4.w = f2bf(sreg[3]);
      l4.x = f2bf(sreg[0]-bfu2f(h4.x)); l4.y = f2bf(sreg[1]-bfu2f(h4.y));
      l4.z = f2bf(sreg[2]-bfu2f(h4.z)); l4.w = f2bf(sreg[3]-bfu2f(h4.w));
      *(ushort4*)&S0h[so] = h4;
      *(ushort4*)&S0l[so] = l4;
    }
  }
}

// rmsnorm(o)*norm_w*silu(z) -> bf16 og; z bf16.
// 256 threads = 4 rows/block.
__global__ __launch_bounds__(256) void gnorm_kernel(
    const float* __restrict__ ob, const unsigned short* __restrict__ zbb,
    const float* __restrict__ norm_w, unsigned short* __restrict__ og) {
  const int tid = threadIdx.x;
  const int idx = blockIdx.x * 4 + (tid >> 6);
  const int lane = tid & 63;
  const int t = idx & 1023;
  const int bh = idx >> 10;
  const int b = bh >> 3;
  const int h = bh & 7;
  const float* o = ob + ((size_t)bh*T_ + t)*128;
  float2 ov = *(const float2*)(o + lane*2);
  float ss = fmaf(ov.x, ov.x, ov.y*ov.y);
  #pragma unroll
  for (int m=1; m<64; m<<=1) ss += __shfl_xor(ss, m);
  float inv = rsqrtf(ss*(1.f/128.f) + 1e-6f);
  size_t zoff = ((size_t)(b*T_+t))*1024 + (size_t)h*128 + lane*2;
  ushort2 zv = *(const ushort2*)(zbb + zoff);
  float z0 = bfu2f(zv.x), z1 = bfu2f(zv.y);
  float n0 = norm_w[lane*2], n1 = norm_w[lane*2+1];
  float r0 = ov.x*inv*n0 * z0/(1.f+expf(-z0));
  float r1 = ov.y*inv*n1 * z1/(1.f+expf(-z1));
  ushort2 ot;
  ot.x = f2bf(r0); ot.y = f2bf(r1);
  *(ushort2*)(og + zoff) = ot;
}

extern "C" void kernel_launch(void* const* d_in, const int* in_sizes, int n_in,
                              void* d_out, int out_size, void* d_ws, size_t ws_size,
                              hipStream_t stream) {
  const float* hs     = (const float*)d_in[0];
  const float* qkv_w  = (const float*)d_in[1];
  const float* z_w    = (const float*)d_in[2];
  const float* b_w    = (const float*)d_in[3];
  const float* a_w    = (const float*)d_in[4];
  const float* conv_w = (const float*)d_in[5];
  const float* dt_bias= (const float*)d_in[6];
  const float* A_log  = (const float*)d_in[7];
  const float* norm_w = (const float*)d_in[8];
  const float* out_w  = (const float*)d_in[9];
  float* out = (float*)d_out;

  char* wsp = (char*)d_ws;
  size_t off = 0;
  auto give = [&](size_t bytes)->char*{
    char* p = wsp + off; off += (bytes + 255) & ~(size_t)255; return p;
  };
  char* big    = give((size_t)MROWS*CONV_DIM_*4);            // 48 MB: k/q hi/lo + v
  unsigned short* zbuf = (unsigned short*)give((size_t)MROWS*1024*2);  // 8 MB
  unsigned short* outw_bf = (unsigned short*)give((size_t)HID_*1024*2); // 2 MB
  char* bufA   = give((size_t)32*T_*128*4);                  // 16 MB
  char* bufB   = give((size_t)32*T_*128*4);                  // 16 MB
  char* bufC   = give((size_t)32*T_*128*4);                  // 16 MB
  float* gbuf  = (float*)give((size_t)32*T_*4);
  float* beta  = (float*)give((size_t)32*T_*4);

  // big (48 MB): fused GEMM+conv outputs
  unsigned short* khi = (unsigned short*)big;                     // 8 MB
  unsigned short* klo = khi + (size_t)4*1024*1024;                // 8 MB
  unsigned short* qhi = klo + (size_t)4*1024*1024;                // 8 MB
  unsigned short* qlo = qhi + (size_t)4*1024*1024;                // 8 MB
  float* vdat = (float*)(qlo + (size_t)4*1024*1024);              // 16 MB
  // bufA: wz_bf [0,2MB) -> Blo [2,6MB) -> og [6,10MB); edge [10,12.25MB)
  unsigned short* wz_bf = (unsigned short*)bufA;
  unsigned short* Blo_g = (unsigned short*)bufA + (size_t)1024*1024;
  unsigned short* og    = (unsigned short*)bufA + (size_t)3*1024*1024;
  float* edge           = (float*)(bufA + (size_t)10*1024*1024);  // 2.25 MB
  // bufB: hs_hi/lo [0,16MB) -> Thi [0,4) Tlo [4,8) Bhi [8,12)
  unsigned short* hs_hi = (unsigned short*)bufB;
  unsigned short* hs_lo = hs_hi + (size_t)MROWS*HID_;
  unsigned short* Thi_g = (unsigned short*)bufB;
  unsigned short* Tlo_g = Thi_g + (size_t)512*4096;
  unsigned short* Bhi_g = Tlo_g + (size_t)512*4096;
  // bufC: wc_hi/lo [0,12.6MB) -> ob [0,16MB)
  unsigned short* wc_hi = (unsigned short*)bufC;
  unsigned short* wc_lo = wc_hi + (size_t)CONV_DIM_*HID_;
  float* ob = (float*)bufC;

  convert_weights_kernel<<<dim3(5120), 256, 0, stream>>>(
      qkv_w, z_w, out_w, wc_hi, wc_lo, wz_bf, outw_bf);
  proj_ba_kernel<<<dim3(MROWS), dim3(128), 0, stream>>>(
      hs, b_w, a_w, dt_bias, A_log, gbuf, beta, hs_hi, hs_lo);
  gemm_split_conv_kernel<<<dim3(32, MROWS/128), 256, 0, stream>>>(
      hs_hi, hs_lo, wc_hi, wc_lo, wz_bf, conv_w, qhi, qlo, khi, klo, vdat, edge, zbuf);
  conv_fix_kernel<<<dim3(32*24), dim3(128), 0, stream>>>(
      edge, conv_w, qhi, qlo, khi, klo, vdat);
  scan_ab_kernel<<<dim3(512), dim3(256), 0, stream>>>(
      qhi, qlo, khi, klo, gbuf, beta, Thi_g, Tlo_g, Bhi_g, Blo_g);
  scan_seq_kernel<<<dim3(256), dim3(512), 0, stream>>>(
      khi, klo, qhi, qlo, vdat, gbuf, beta, Thi_g, Tlo_g, Bhi_g, Blo_g, ob);
  gnorm_kernel<<<dim3(32*T_/4), dim3(256), 0, stream>>>(ob, zbuf, norm_w, og);
  gemm_mfma_kernel<0><<<dim3(1024/128, MROWS/128), 256, 0, stream>>>(og, outw_bf, out, MROWS, 1024, HID_);
}

// Round 15
// 333.182 us; speedup vs baseline: 1.0261x; 1.0080x over previous
//
#include <hip/hip_runtime.h>

#define B_ 4
#define T_ 1024
#define HID_ 1024
#define H_ 8
#define CONV_DIM_ 3072
#define MROWS (B_*T_)

typedef __bf16 bf16x8 __attribute__((ext_vector_type(8)));
typedef float f32x4 __attribute__((ext_vector_type(4)));

#define MFMA16(a,b,c) __builtin_amdgcn_mfma_f32_16x16x32_bf16((a),(b),(c),0,0,0)

static __device__ __forceinline__ unsigned short f2bf(float f) {
  unsigned u = __float_as_uint(f);
  unsigned r = u + 0x7fffu + ((u >> 16) & 1u);   // RNE
  return (unsigned short)(r >> 16);
}
static __device__ __forceinline__ float bfu2f(unsigned short v) {
  return __uint_as_float(((unsigned)v) << 16);
}
static __device__ __forceinline__ float4 recon4(ushort4 h, ushort4 l) {
  float4 r;
  r.x = bfu2f(h.x) + bfu2f(l.x);
  r.y = bfu2f(h.y) + bfu2f(l.y);
  r.z = bfu2f(h.z) + bfu2f(l.z);
  r.w = bfu2f(h.w) + bfu2f(l.w);
  return r;
}

// async global->LDS 16B. LDS dest must be wave-uniform base + lane*16 (m104/m108).
static __device__ __forceinline__ void gld16(void* lds, const void* g) {
  __builtin_amdgcn_global_load_lds(
      (const __attribute__((address_space(1))) unsigned int*)g,
      (__attribute__((address_space(3))) unsigned int*)lds, 16, 0, 0);
}

// Merged front-end: weight conversions AND bb/aa projections in ONE dispatch
// (independent workloads; co-scheduling shares the HBM pipe instead of
// serializing two memory-bound launches).
//   bid < 3072          : qkv_w -> hi/lo split
//   3072 <= bid < 4096  : z_w -> bf16
//   4096 <= bid < 5120  : out_w -> bf16
//   bid >= 5120         : proj_ba path, 2 rows per block (256 thr = 2x128)
__global__ __launch_bounds__(256) void prep_kernel(
    const float* __restrict__ qkv_w, const float* __restrict__ z_w,
    const float* __restrict__ out_w,
    unsigned short* __restrict__ wc_hi, unsigned short* __restrict__ wc_lo,
    unsigned short* __restrict__ wz_bf, unsigned short* __restrict__ outw_bf,
    const float* __restrict__ hs, const float* __restrict__ b_w,
    const float* __restrict__ a_w, const float* __restrict__ dt_bias,
    const float* __restrict__ A_log,
    float* __restrict__ gout, float* __restrict__ beta,
    unsigned short* __restrict__ hs_hi, unsigned short* __restrict__ hs_lo) {
  const int bid = blockIdx.x;
  const int tid = threadIdx.x;
  if (bid < 3072) {
    int i = (bid * 256 + tid) * 4;
    float4 v = *(const float4*)(qkv_w + i);
    ushort4 h, l;
    h.x = f2bf(v.x); h.y = f2bf(v.y); h.z = f2bf(v.z); h.w = f2bf(v.w);
    l.x = f2bf(v.x - bfu2f(h.x));
    l.y = f2bf(v.y - bfu2f(h.y));
    l.z = f2bf(v.z - bfu2f(h.z));
    l.w = f2bf(v.w - bfu2f(h.w));
    *(ushort4*)(wc_hi + i) = h;
    *(ushort4*)(wc_lo + i) = l;
    return;
  }
  if (bid < 5120) {
    const bool isZ = (bid < 4096);
    const float* src = isZ ? z_w : out_w;
    unsigned short* dst = isZ ? wz_bf : outw_bf;
    int i = (((bid - (isZ ? 3072 : 4096)) * 256) + tid) * 4;
    float4 v = *(const float4*)(src + i);
    ushort4 o;
    o.x = f2bf(v.x); o.y = f2bf(v.y); o.z = f2bf(v.z); o.w = f2bf(v.w);
    *(ushort4*)(dst + i) = o;
    return;
  }
  // ---- proj_ba path: 2 rows per block, 128 threads each
  const int pb = bid - 5120;
  const int ltid = tid & 127;
  const int bt = pb * 2 + (tid >> 7);
  const int b = bt >> 10;
  const int t = bt & 1023;
  const int grp = ltid >> 3;
  const int l8 = ltid & 7;
  const int h = grp & 7;
  const bool isA = grp >= 8;
  const float* w = (isA ? a_w : b_w) + (size_t)h * HID_;
  const float* x = hs + (size_t)bt * HID_;
  // coalesced hs -> bf16 hi/lo emit: 128 threads x 8 elems per row
  {
    const int e = ltid * 8;
    float4 xv0 = *(const float4*)(x + e);
    float4 xv1 = *(const float4*)(x + e + 4);
    ushort4 h0, l0, h1, l1;
    h0.x = f2bf(xv0.x); h0.y = f2bf(xv0.y); h0.z = f2bf(xv0.z); h0.w = f2bf(xv0.w);
    l0.x = f2bf(xv0.x - bfu2f(h0.x)); l0.y = f2bf(xv0.y - bfu2f(h0.y));
    l0.z = f2bf(xv0.z - bfu2f(h0.z)); l0.w = f2bf(xv0.w - bfu2f(h0.w));
    h1.x = f2bf(xv1.x); h1.y = f2bf(xv1.y); h1.z = f2bf(xv1.z); h1.w = f2bf(xv1.w);
    l1.x = f2bf(xv1.x - bfu2f(h1.x)); l1.y = f2bf(xv1.y - bfu2f(h1.y));
    l1.z = f2bf(xv1.z - bfu2f(h1.z)); l1.w = f2bf(xv1.w - bfu2f(h1.w));
    unsigned short* hho = hs_hi + (size_t)bt * HID_ + e;
    unsigned short* hlo = hs_lo + (size_t)bt * HID_ + e;
    *(ushort4*)hho = h0;       *(ushort4*)hlo = l0;
    *(ushort4*)(hho + 4) = h1; *(ushort4*)(hlo + 4) = l1;
  }
  float s = 0.f;
  for (int e = l8*4; e < HID_; e += 32){
    float4 xv = *(const float4*)(x + e);
    float4 wv = *(const float4*)(w + e);
    s = fmaf(xv.x, wv.x, s);
    s = fmaf(xv.y, wv.y, s);
    s = fmaf(xv.z, wv.z, s);
    s = fmaf(xv.w, wv.w, s);
  }
  // 8-lane cluster reduce (xor 1/2/4 stays inside one wave for any 128-group)
  s += __shfl_xor(s,1); s += __shfl_xor(s,2); s += __shfl_xor(s,4);
  if (l8 == 0) {
    size_t o = ((size_t)(b*H_ + h))*T_ + t;
    if (!isA) {
      beta[o] = 1.f/(1.f+expf(-s));
    } else {
      float xx = s + dt_bias[h];
      float sp = fmaxf(xx,0.f) + log1pf(expf(-fabsf(xx)));   // softplus
      gout[o] = -expf(A_log[h]) * sp;                        // g = log(alpha)
    }
  }
}

// Single-pass bf16 MFMA GEMM: C[M,N] = A[M,K] * W[N,K]^T. 128x128 tile, BK=32.
template<int OUT_BF16>
__global__ __launch_bounds__(256) void gemm_mfma_kernel(
    const unsigned short* __restrict__ A, const unsigned short* __restrict__ W,
    void* __restrict__ Cv, int M, int N, int K) {
  __shared__ __align__(16) unsigned short lA[128*32];
  __shared__ __align__(16) unsigned short lB[128*32];
  const int tid  = threadIdx.x;
  const int lane = tid & 63;
  const int wv   = tid >> 6;
  const int wm   = (wv >> 1) * 64;
  const int wn   = (wv & 1) * 64;
  const int m16  = lane & 15;
  const int quad = lane >> 4;
  const int bm = blockIdx.y * 128;
  const int bn = blockIdx.x * 128;

  f32x4 acc[4][4];
  #pragma unroll
  for (int i = 0; i < 4; ++i)
    #pragma unroll
    for (int j = 0; j < 4; ++j)
      acc[i][j] = (f32x4){0.f, 0.f, 0.f, 0.f};

  const int r0 = tid >> 2, c0 = tid & 3;
  const int r1 = r0 + 64;
  const int g0 = (c0 ^ (r0 & 3)) * 8;
  const int g1 = (c0 ^ (r1 & 3)) * 8;
  const unsigned short* Ar0 = A + (size_t)(bm + r0) * K + g0;
  const unsigned short* Ar1 = A + (size_t)(bm + r1) * K + g1;
  const unsigned short* Wr0 = W + (size_t)(bn + r0) * K + g0;
  const unsigned short* Wr1 = W + (size_t)(bn + r1) * K + g1;
  unsigned short* sA0 = &lA[(size_t)tid * 8];
  unsigned short* sA1 = &lA[(size_t)(tid + 256) * 8];
  unsigned short* sB0 = &lB[(size_t)tid * 8];
  unsigned short* sB1 = &lB[(size_t)(tid + 256) * 8];

  int offA[4], offB[4];
  #pragma unroll
  for (int i = 0; i < 4; ++i) {
    int ra = wm + i * 16 + m16;
    offA[i] = ra * 32 + (quad ^ (ra & 3)) * 8;
    int rb = wn + i * 16 + m16;
    offB[i] = rb * 32 + (quad ^ (rb & 3)) * 8;
  }

  for (int k0 = 0; k0 < K; k0 += 32) {
    gld16(sA0, Ar0 + k0);
    gld16(sA1, Ar1 + k0);
    gld16(sB0, Wr0 + k0);
    gld16(sB1, Wr1 + k0);
    __syncthreads();
    bf16x8 af[4], bfr[4];
    #pragma unroll
    for (int i = 0; i < 4; ++i) {
      af[i]  = *(const bf16x8*)&lA[offA[i]];
      bfr[i] = *(const bf16x8*)&lB[offB[i]];
    }
    #pragma unroll
    for (int mi = 0; mi < 4; ++mi)
      #pragma unroll
      for (int ni = 0; ni < 4; ++ni)
        acc[mi][ni] = MFMA16(af[mi], bfr[ni], acc[mi][ni]);
    __syncthreads();
  }

  #pragma unroll
  for (int mi = 0; mi < 4; ++mi) {
    #pragma unroll
    for (int r = 0; r < 4; ++r) {
      size_t row = (size_t)(bm + wm + mi * 16 + quad * 4 + r);
      #pragma unroll
      for (int ni = 0; ni < 4; ++ni) {
        int col = bn + wn + ni * 16 + m16;
        float val = acc[mi][ni][r];
        if (OUT_BF16) ((unsigned short*)Cv)[row * N + col] = f2bf(val);
        else          ((float*)Cv)[row * N + col] = val;
      }
    }
  }
}

// Fused: split-precision MFMA GEMM (mixed = hs.qkv_w^T, 3 products) + causal
// depthwise conv (K=4) epilogue, PLUS merged z-projection on blocks x>=24.
// NOTE (round-11 lesson): the Alo.Whi term is REQUIRED — dropping it gave
// absmax 0.18 (the scan recurrence amplifies q/k operand error ~100x).
// Epilogue: two 64-row half-tiles through [64][132] fp32 LDS (35328B total).
__global__ __launch_bounds__(256) void gemm_split_conv_kernel(
    const unsigned short* __restrict__ Ahi, const unsigned short* __restrict__ Alo,
    const unsigned short* __restrict__ Whi, const unsigned short* __restrict__ Wlo,
    const unsigned short* __restrict__ Wz,
    const float* __restrict__ conv_w,
    unsigned short* __restrict__ qhi, unsigned short* __restrict__ qlo,
    unsigned short* __restrict__ khi, unsigned short* __restrict__ klo,
    float* __restrict__ vb, float* __restrict__ edge,
    unsigned short* __restrict__ zbuf) {
  __shared__ __align__(16) unsigned char ldsraw[64*132*4 + 3*128*4];
  unsigned short* lAh = (unsigned short*)ldsraw;
  unsigned short* lAl = lAh + 128*32;
  unsigned short* lBh = lAl + 128*32;
  unsigned short* lBl = lBh + 128*32;
  float* smX2  = (float*)ldsraw;
  float* carry = (float*)(ldsraw + 64*132*4);

  const int tid  = threadIdx.x;
  const int lane = tid & 63;
  const int wv   = tid >> 6;
  const int wm   = (wv >> 1) * 64;
  const int wn   = (wv & 1) * 64;
  const int m16  = lane & 15;
  const int quad = lane >> 4;
  const int bm = blockIdx.y * 128;

  f32x4 acc[4][4];
  #pragma unroll
  for (int i = 0; i < 4; ++i)
    #pragma unroll
    for (int j = 0; j < 4; ++j)
      acc[i][j] = (f32x4){0.f, 0.f, 0.f, 0.f};

  const int r0 = tid >> 2, c0 = tid & 3;
  const int r1 = r0 + 64;
  const int g0 = (c0 ^ (r0 & 3)) * 8;
  const int g1 = (c0 ^ (r1 & 3)) * 8;
  const size_t oA0 = (size_t)(bm + r0) * 1024 + g0;
  const size_t oA1 = (size_t)(bm + r1) * 1024 + g1;
  const int s0 = tid * 8, s1 = (tid + 256) * 8;

  int offA[4], offB[4];
  #pragma unroll
  for (int i = 0; i < 4; ++i) {
    int ra = wm + i * 16 + m16;
    offA[i] = ra * 32 + (quad ^ (ra & 3)) * 8;
    int rb = wn + i * 16 + m16;
    offB[i] = rb * 32 + (quad ^ (rb & 3)) * 8;
  }

  // ---- z path (blocks x>=24): z = hs_hi . z_w^T, single product, bf16 out.
  if (blockIdx.x >= 24) {
    const int bn = (blockIdx.x - 24) * 128;
    const size_t oBz0 = (size_t)(bn + r0) * 1024 + g0;
    const size_t oBz1 = (size_t)(bn + r1) * 1024 + g1;
    for (int k0 = 0; k0 < 1024; k0 += 32) {
      gld16(&lAh[s0], Ahi + oA0 + k0);
      gld16(&lAh[s1], Ahi + oA1 + k0);
      gld16(&lBh[s0], Wz + oBz0 + k0);
      gld16(&lBh[s1], Wz + oBz1 + k0);
      __syncthreads();
      bf16x8 af[4], bfr[4];
      #pragma unroll
      for (int i = 0; i < 4; ++i) {
        af[i]  = *(const bf16x8*)&lAh[offA[i]];
        bfr[i] = *(const bf16x8*)&lBh[offB[i]];
      }
      #pragma unroll
      for (int mi = 0; mi < 4; ++mi)
        #pragma unroll
        for (int ni = 0; ni < 4; ++ni)
          acc[mi][ni] = MFMA16(af[mi], bfr[ni], acc[mi][ni]);
      __syncthreads();
    }
    #pragma unroll
    for (int mi = 0; mi < 4; ++mi) {
      #pragma unroll
      for (int r = 0; r < 4; ++r) {
        size_t row = (size_t)(bm + wm + mi * 16 + quad * 4 + r);
        #pragma unroll
        for (int ni = 0; ni < 4; ++ni)
          zbuf[row * 1024 + bn + wn + ni * 16 + m16] = f2bf(acc[mi][ni][r]);
      }
    }
    return;
  }

  // ---- qkv path (blocks x<24)
  const int bn = blockIdx.x * 128;
  const size_t oB0 = (size_t)(bn + r0) * 1024 + g0;
  const size_t oB1 = (size_t)(bn + r1) * 1024 + g1;

  for (int k0 = 0; k0 < 1024; k0 += 32) {
    gld16(&lAh[s0], Ahi + oA0 + k0);
    gld16(&lAh[s1], Ahi + oA1 + k0);
    gld16(&lAl[s0], Alo + oA0 + k0);
    gld16(&lAl[s1], Alo + oA1 + k0);
    gld16(&lBh[s0], Whi + oB0 + k0);
    gld16(&lBh[s1], Whi + oB1 + k0);
    gld16(&lBl[s0], Wlo + oB0 + k0);
    gld16(&lBl[s1], Wlo + oB1 + k0);
    __syncthreads();
    bf16x8 afh[4], bfh[4];
    #pragma unroll
    for (int i = 0; i < 4; ++i) {
      afh[i] = *(const bf16x8*)&lAh[offA[i]];
      bfh[i] = *(const bf16x8*)&lBh[offB[i]];
    }
    #pragma unroll
    for (int mi = 0; mi < 4; ++mi)
      #pragma unroll
      for (int ni = 0; ni < 4; ++ni)
        acc[mi][ni] = MFMA16(afh[mi], bfh[ni], acc[mi][ni]);
    {
      bf16x8 bfl[4];
      #pragma unroll
      for (int i = 0; i < 4; ++i) bfl[i] = *(const bf16x8*)&lBl[offB[i]];
      #pragma unroll
      for (int mi = 0; mi < 4; ++mi)
        #pragma unroll
        for (int ni = 0; ni < 4; ++ni)
          acc[mi][ni] = MFMA16(afh[mi], bfl[ni], acc[mi][ni]);
    }
    {
      bf16x8 afl[4];
      #pragma unroll
      for (int i = 0; i < 4; ++i) afl[i] = *(const bf16x8*)&lAl[offA[i]];
      #pragma unroll
      for (int mi = 0; mi < 4; ++mi)
        #pragma unroll
        for (int ni = 0; ni < 4; ++ni)
          acc[mi][ni] = MFMA16(afl[mi], bfh[ni], acc[mi][ni]);
    }
    __syncthreads();   // last iter: all staging reads done -> smX2 alias safe
  }

  // ---- epilogue: two 64-row half-tiles
  const int bi = blockIdx.y;
  const int c  = tid & 127;
  const int rh = tid >> 7;
  const int cg = bn + c;
  const int part = cg >> 10;         // block-uniform
  const int hh = (cg & 1023) >> 7;   // block-uniform
  const int b = bm >> 10;
  const int tloc0 = bm & 1023;
  float4 w4 = *(const float4*)(conv_w + cg * 4);
  size_t rowb = ((size_t)(b * H_ + hh)) * T_;
  unsigned short* dh = (part == 0) ? qhi : khi;
  unsigned short* dl = (part == 0) ? qlo : klo;

  #pragma unroll
  for (int half = 0; half < 2; ++half) {
    if (half == 1) __syncthreads();   // half-0 conv reads + carry save done
    if ((wv >> 1) == half) {
      #pragma unroll
      for (int mi = 0; mi < 4; ++mi)
        #pragma unroll
        for (int r = 0; r < 4; ++r) {
          int row = mi * 16 + quad * 4 + r;
          #pragma unroll
          for (int ni = 0; ni < 4; ++ni)
            smX2[row * 132 + wn + ni * 16 + m16] = acc[mi][ni][r];
        }
    }
    __syncthreads();
    // edge spill + (half 0) carry save — 384 items via e*256+tid (256 threads)
    if (half == 0) {
      #pragma unroll
      for (int e = 0; e < 2; ++e) {
        int idx = e * 256 + tid;
        int r = idx >> 7, cc = idx & 127;
        if (r < 3) {
          edge[((size_t)bi*6 + 3 + r)*3072 + bn + cc] = smX2[r*132 + cc];
          carry[r*128 + cc] = smX2[(61+r)*132 + cc];
        }
      }
    } else {
      if (bi < 31) {
        #pragma unroll
        for (int e = 0; e < 2; ++e) {
          int idx = e * 256 + tid;
          int r = idx >> 7, cc = idx & 127;
          if (r < 3)
            edge[((size_t)(bi+1)*6 + r)*3072 + bn + cc] = smX2[(61+r)*132 + cc];
        }
      }
    }
    // conv: 2 threads/col, 32 t-steps each
    {
      const int tb0 = rh * 32;
      float x0, x1, x2;
      if (tb0 >= 3) {
        x0 = smX2[(tb0-3)*132 + c];
        x1 = smX2[(tb0-2)*132 + c];
        x2 = smX2[(tb0-1)*132 + c];
      } else {  // tb0 == 0
        if (half == 0) { x0 = 0.f; x1 = 0.f; x2 = 0.f; }
        else { x0 = carry[0*128 + c]; x1 = carry[1*128 + c]; x2 = carry[2*128 + c]; }
      }
      for (int tt = 0; tt < 32; ++tt) {
        const int t = tb0 + tt;
        float x3 = smX2[t*132 + c];
        float s = fmaf(w4.x, x0, fmaf(w4.y, x1, fmaf(w4.z, x2, w4.w * x3)));
        x0 = x1; x1 = x2; x2 = x3;
        const int tg = tloc0 + half*64 + t;
        if (part == 2) {
          vb[(rowb + tg) * 128 + c] = s;
        } else {
          int sw = (((c >> 3) ^ (tg & 7)) << 3) + (c & 7);
          unsigned short hv = f2bf(s);
          dh[(rowb + tg) * 128 + sw] = hv;
          dl[(rowb + tg) * 128 + sw] = f2bf(s - bfu2f(hv));
        }
      }
    }
  }
}

// Boundary fixup (trivial): 6 mixed rows come straight from the edge buffer.
__global__ __launch_bounds__(128) void conv_fix_kernel(
    const float* __restrict__ edge, const float* __restrict__ conv_w,
    unsigned short* __restrict__ qhi, unsigned short* __restrict__ qlo,
    unsigned short* __restrict__ khi, unsigned short* __restrict__ klo,
    float* __restrict__ vb) {
  const int bi = blockIdx.x / 24;
  const int cb = blockIdx.x % 24;
  const int bm = bi * 128, n0 = cb * 128;
  const int b = bm >> 10, tloc = bm & 1023;
  const int c = threadIdx.x;
  const int cg = n0 + c;
  float m[6];
  #pragma unroll
  for (int j = 0; j < 6; ++j)
    m[j] = edge[((size_t)bi*6 + j)*3072 + cg];
  if (tloc == 0) { m[0] = 0.f; m[1] = 0.f; m[2] = 0.f; }
  const int part = cg >> 10;
  const int hh = (cg & 1023) >> 7;
  float4 w4 = *(const float4*)(conv_w + cg * 4);
  size_t rowb = ((size_t)(b * H_ + hh)) * T_;
  unsigned short* dh = (part == 0) ? qhi : khi;
  unsigned short* dl = (part == 0) ? qlo : klo;
  #pragma unroll
  for (int jo = 0; jo < 3; ++jo) {
    float s = fmaf(w4.x, m[jo], fmaf(w4.y, m[jo+1],
              fmaf(w4.z, m[jo+2], w4.w * m[jo+3])));
    const int tg = tloc + jo;
    if (part == 2) {
      vb[(rowb + tg) * 128 + c] = s;
    } else {
      int sw = (((c >> 3) ^ (tg & 7)) << 3) + (c & 7);
      unsigned short hv = f2bf(s);
      dh[(rowb + tg) * 128 + sw] = hv;
      dl[(rowb + tg) * 128 + sw] = f2bf(s - bfu2f(hv));
    }
  }
}

// Parallel precompute: 512 blocks = (bh, chunk). MFMA version.
// T = (I+A)^-1 (unit lower), B = incl-lower decayed QK^T.
__global__ __launch_bounds__(256) void scan_ab_kernel(
    const unsigned short* __restrict__ qhi_g, const unsigned short* __restrict__ qlo_g,
    const unsigned short* __restrict__ khi_g, const unsigned short* __restrict__ klo_g,
    const float* __restrict__ gbuf, const float* __restrict__ bbuf,
    unsigned short* __restrict__ Thi_g, unsigned short* __restrict__ Tlo_g,
    unsigned short* __restrict__ Bhi_g, unsigned short* __restrict__ Blo_g) {
  const int blk = blockIdx.x;
  const int bh = blk >> 4;
  const int ch = blk & 15;
  const int t0 = ch * 64;
  const int tid = threadIdx.x;
  const int wvb = tid >> 6;          // wave = output row-block
  const int lane = tid & 63;
  const int v16 = lane & 15;
  const int quad = lane >> 4;
  __shared__ float sAA[64][68];
  __shared__ float lL[64];
  __shared__ float bL[64];
  unsigned short* Tho = Thi_g + (size_t)blk*4096;
  unsigned short* Tlo = Tlo_g + (size_t)blk*4096;
  unsigned short* Bho = Bhi_g + (size_t)blk*4096;
  unsigned short* Blo = Blo_g + (size_t)blk*4096;
  const unsigned short* kh  = khi_g + (size_t)bh*131072 + (size_t)t0*128;
  const unsigned short* klp = klo_g + (size_t)bh*131072 + (size_t)t0*128;
  const unsigned short* qh  = qhi_g + (size_t)bh*131072 + (size_t)t0*128;
  const unsigned short* qlp = qlo_g + (size_t)bh*131072 + (size_t)t0*128;

  if (tid < 64) {
    float x = gbuf[(size_t)bh*T_ + t0 + tid];
    #pragma unroll
    for (int o = 1; o < 64; o <<= 1) {
      float y = __shfl_up(x, o);
      if (tid >= o) x += y;
    }
    lL[tid] = x;
    bL[tid] = bbuf[(size_t)bh*T_ + t0 + tid];
  }

  const int ar = wvb*16 + v16;
  const int arx = ar & 7;
  bf16x8 kAh[4], kAl[4], qAh[4], qAl[4];
  #pragma unroll
  for (int ks = 0; ks < 4; ++ks) {
    const int u = 4*ks + quad;
    const int ao = ar*128 + ((u ^ arx) << 3);
    kAh[ks] = *(const bf16x8*)&kh[ao];
    kAl[ks] = *(const bf16x8*)&klp[ao];
    qAh[ks] = *(const bf16x8*)&qh[ao];
    qAl[ks] = *(const bf16x8*)&qlp[ao];
  }
  __syncthreads();   // lL/bL ready

  const int i0 = wvb*16 + quad*4;
  float biv[4], liv[4];
  #pragma unroll
  for (int r = 0; r < 4; ++r) { biv[r] = bL[i0+r]; liv[r] = lL[i0+r]; }

  #pragma unroll
  for (int cb = 0; cb < 4; ++cb) {
    const int j = cb*16 + v16;
    if (cb <= wvb) {
      const int rb = cb*16 + v16;
      const int rbx = rb & 7;
      f32x4 a1 = (f32x4){0.f,0.f,0.f,0.f}, a2 = (f32x4){0.f,0.f,0.f,0.f};
      f32x4 q1 = (f32x4){0.f,0.f,0.f,0.f}, q2 = (f32x4){0.f,0.f,0.f,0.f};
      #pragma unroll
      for (int ks = 0; ks < 4; ++ks) {
        const int u = 4*ks + quad;
        const int bo = rb*128 + ((u ^ rbx) << 3);
        bf16x8 bhv = *(const bf16x8*)&kh[bo];
        bf16x8 blv = *(const bf16x8*)&klp[bo];
        a1 = MFMA16(kAh[ks], bhv, a1);
        a2 = MFMA16(kAh[ks], blv, a2);
        a2 = MFMA16(kAl[ks], bhv, a2);
        q1 = MFMA16(qAh[ks], bhv, q1);
        q2 = MFMA16(qAh[ks], blv, q2);
        q2 = MFMA16(qAl[ks], bhv, q2);
      }
      float lj = lL[j];
      #pragma unroll
      for (int r = 0; r < 4; ++r) {
        const int i = i0 + r;
        float av = a1[r] + a2[r];
        float qv = q1[r] + q2[r];
        sAA[i][j] = (j < i) ? biv[r] * __expf(liv[r] - lj) * av : 0.f;
        float xq = (j <= i) ? __expf(liv[r] - lj) * qv : 0.f;
        unsigned short hv = f2bf(xq);
        int sidx = i*64 + (((j>>3) ^ (i&7)) << 3) + (j&7);
        Bho[sidx] = hv;
        Blo[sidx] = f2bf(xq - bfu2f(hv));
      }
    } else {
      #pragma unroll
      for (int r = 0; r < 4; ++r) {
        const int i = i0 + r;
        sAA[i][j] = 0.f;
        int sidx = i*64 + (((j>>3) ^ (i&7)) << 3) + (j&7);
        Bho[sidx] = 0;
        Blo[sidx] = 0;
      }
    }
  }
  __syncthreads();

  // invert (I+A): 4 waves x 16 cols, rows rr+4m per thread; wave-local chain
  {
    const int w = tid >> 6;
    const int ln = tid & 63;
    const int colc = w*16 + (ln & 15);
    const int rr = ln >> 4;
    float rh[16];
    #pragma unroll
    for (int m=0;m<16;++m) rh[m] = (rr + 4*m == colc) ? 1.f : 0.f;
    for (int j = 0; j < 63; ++j) {
      int src = ((j & 3) << 4) | (ln & 15);
      float wj = __shfl(rh[j >> 2], src);
      #pragma unroll
      for (int m=0;m<16;++m)
        rh[m] = fmaf(-sAA[rr + 4*m][j], wj, rh[m]);
    }
    #pragma unroll
    for (int m=0;m<16;++m) {
      int i2 = rr + 4*m;
      float x = rh[m];
      unsigned short hv = f2bf(x);
      int sidx = i2*64 + (((colc>>3) ^ (i2&7)) << 3) + (colc&7);
      Tho[sidx] = hv;
      Tlo[sidx] = f2bf(x - bfu2f(hv));
    }
  }
}

// Sequential chunked scan, 512 threads (8 waves), UT-transform, all-MFMA phases.
// XCD-aware block decode: bh = bid&31, sl = bid>>5.
__global__ __launch_bounds__(512) void scan_seq_kernel(
    const unsigned short* __restrict__ khi_g, const unsigned short* __restrict__ klo_g,
    const unsigned short* __restrict__ qhi_g, const unsigned short* __restrict__ qlo_g,
    const float* __restrict__ vb,
    const float* __restrict__ gbuf, const float* __restrict__ bbuf,
    const unsigned short* __restrict__ Thi_g, const unsigned short* __restrict__ Tlo_g,
    const unsigned short* __restrict__ Bhi_g, const unsigned short* __restrict__ Blo_g,
    float* __restrict__ ob) {
  const int bh = blockIdx.x & 31;
  const int sl = blockIdx.x >> 5;
  const int tid = threadIdx.x;
  const int wv = tid >> 6;
  const int lane = tid & 63;
  const int v16 = lane & 15;
  const int quad = lane >> 4;
  const int tb = (wv & 3) * 16;
  const bool isQ = (wv >= 4);
  const int vx = v16 & 7;

  __shared__ __align__(16) unsigned short KhiL[2][64*128];
  __shared__ __align__(16) unsigned short KloL[2][64*128];
  __shared__ __align__(16) unsigned short WTh[16*64],  WTl[16*64];
  __shared__ __align__(16) unsigned short W2Th[16*64], W2Tl[16*64];
  __shared__ __align__(16) unsigned short W3Th[16*64], W3Tl[16*64];
  __shared__ __align__(16) unsigned short S0h[16*128], S0l[16*128];

  const unsigned short* kh  = khi_g + (size_t)bh*131072;
  const unsigned short* klp = klo_g + (size_t)bh*131072;
  const unsigned short* qh  = qhi_g + (size_t)bh*131072;
  const unsigned short* qlp = qlo_g + (size_t)bh*131072;
  const float* vg = vb + (size_t)bh*T_*128 + sl*16;
  const float* gg = gbuf + (size_t)bh*T_;
  const float* beg = bbuf + (size_t)bh*T_;
  float* og = ob + (size_t)bh*T_*128 + sl*16;

  f32x4 sreg = (f32x4){0.f, 0.f, 0.f, 0.f};
  const int kk0 = wv*16 + v16;
  const int k8 = kk0 >> 3, k7 = kk0 & 7;
  const int kq4 = (quad & 1) * 4;
  const int kr8 = (wv*16 + quad*4) >> 3;

  gld16(&KhiL[0][tid*8],        kh + tid*8);
  gld16(&KhiL[0][4096 + tid*8], kh + 4096 + tid*8);
  gld16(&KloL[0][tid*8],        klp + tid*8);
  gld16(&KloL[0][4096 + tid*8], klp + 4096 + tid*8);

  for (int ch = 0; ch < 16; ++ch) {
    const int t0 = ch * 64;
    const int cur = ch & 1;
    __syncthreads();

    if (ch < 15) {
      const size_t co = (size_t)(t0 + 64) * 128;
      gld16(&KhiL[cur^1][tid*8],        kh + co + tid*8);
      gld16(&KhiL[cur^1][4096 + tid*8], kh + co + 4096 + tid*8);
      gld16(&KloL[cur^1][tid*8],        klp + co + tid*8);
      gld16(&KloL[cur^1][4096 + tid*8], klp + co + 4096 + tid*8);
    }

    float gv = gg[t0 + lane];
    #pragma unroll
    for (int o = 1; o < 64; o <<= 1) {
      float y = __shfl_up(gv, o);
      if (lane >= o) gv += y;
    }
    float bv = beg[t0 + lane];

    const int ar = tb + v16;
    const int arx = ar & 7;
    const size_t tbo = ((size_t)(bh*16 + ch)) * 4096;
    bf16x8 tfh0, tfh1, tfl0, tfl1;
    bf16x8 bfh0, bfh1, bfl0, bfl1;
    bf16x8 qfh[4], qfl[4];
    if (!isQ) {
      int a0 = ar*64 + ((quad ^ arx) << 3);
      int a1 = ar*64 + (((4 + quad) ^ arx) << 3);
      tfh0 = *(const bf16x8*)&Thi_g[tbo + a0];
      tfh1 = *(const bf16x8*)&Thi_g[tbo + a1];
      tfl0 = *(const bf16x8*)&Tlo_g[tbo + a0];
      tfl1 = *(const bf16x8*)&Tlo_g[tbo + a1];
    } else {
      int a0 = ar*64 + ((quad ^ arx) << 3);
      int a1 = ar*64 + (((4 + quad) ^ arx) << 3);
      bfh0 = *(const bf16x8*)&Bhi_g[tbo + a0];
      bfh1 = *(const bf16x8*)&Bhi_g[tbo + a1];
      bfl0 = *(const bf16x8*)&Blo_g[tbo + a0];
      bfl1 = *(const bf16x8*)&Blo_g[tbo + a1];
      const size_t qco = (size_t)t0 * 128;
      #pragma unroll
      for (int ks = 0; ks < 4; ++ks) {
        int ao = ar*128 + (((4*ks + quad) ^ arx) << 3);
        qfh[ks] = *(const bf16x8*)&qh[qco + ao];
        qfl[ks] = *(const bf16x8*)&qlp[qco + ao];
      }
    }

    f32x4 facc = (f32x4){0.f,0.f,0.f,0.f};
    if (ch) {
      f32x4 f2 = (f32x4){0.f,0.f,0.f,0.f};
      #pragma unroll
      for (int ks = 0; ks < 4; ++ks) {
        const int u = 4*ks + quad;
        const int bo = v16*128 + ((u ^ vx) << 3);
        bf16x8 bhi = *(const bf16x8*)&S0h[bo];
        bf16x8 blo = *(const bf16x8*)&S0l[bo];
        bf16x8 ahi, alo;
        if (!isQ) {
          const int ao = ar*128 + ((u ^ arx) << 3);
          ahi = *(const bf16x8*)&KhiL[cur][ao];
          alo = *(const bf16x8*)&KloL[cur][ao];
        } else {
          ahi = qfh[ks]; alo = qfl[ks];
        }
        facc = MFMA16(ahi, bhi, facc);
        f2   = MFMA16(ahi, blo, f2);
        f2   = MFMA16(alo, bhi, f2);
      }
      facc[0] += f2[0]; facc[1] += f2[1]; facc[2] += f2[2]; facc[3] += f2[3];
    }
    const int t4 = tb + quad*4;
    const int wo = v16*64 + ((((t4>>3) ^ vx)) << 3) + (t4 & 7);
    f32x4 qacc = facc;
    if (!isQ) {
      float xr[4];
      #pragma unroll
      for (int r = 0; r < 4; ++r) {
        const int t = t4 + r;
        float be = __shfl(bv, t);
        float ga = __expf(__shfl(gv, t));
        float vvv = vg[(size_t)(t0 + t)*128 + v16];
        xr[r] = fmaf(-be*ga, facc[r], be*vvv);
      }
      ushort4 h4, l4;
      h4.x = f2bf(xr[0]); h4.y = f2bf(xr[1]); h4.z = f2bf(xr[2]); h4.w = f2bf(xr[3]);
      l4.x = f2bf(xr[0]-bfu2f(h4.x)); l4.y = f2bf(xr[1]-bfu2f(h4.y));
      l4.z = f2bf(xr[2]-bfu2f(h4.z)); l4.w = f2bf(xr[3]-bfu2f(h4.w));
      *(ushort4*)&WTh[wo] = h4;
      *(ushort4*)&WTl[wo] = l4;
    }
    __syncthreads();

    if (!isQ) {
      f32x4 wa = (f32x4){0.f,0.f,0.f,0.f};
      f32x4 wb = (f32x4){0.f,0.f,0.f,0.f};
      {
        const int b0 = v16*64 + ((quad ^ vx) << 3);
        const int b1 = v16*64 + (((4 + quad) ^ vx) << 3);
        bf16x8 r0h = *(const bf16x8*)&WTh[b0];
        bf16x8 r0l = *(const bf16x8*)&WTl[b0];
        bf16x8 r1h = *(const bf16x8*)&WTh[b1];
        bf16x8 r1l = *(const bf16x8*)&WTl[b1];
        wa = MFMA16(tfh0, r0h, wa);
        wb = MFMA16(tfh0, r0l, wb);
        wb = MFMA16(tfl0, r0h, wb);
        wa = MFMA16(tfh1, r1h, wa);
        wb = MFMA16(tfh1, r1l, wb);
        wb = MFMA16(tfl1, r1h, wb);
      }
      float Le = __shfl(gv, 63);
      float x0 = wa[0]+wb[0], x1 = wa[1]+wb[1], x2 = wa[2]+wb[2], x3 = wa[3]+wb[3];
      ushort4 h4, l4;
      h4.x = f2bf(x0); h4.y = f2bf(x1); h4.z = f2bf(x2); h4.w = f2bf(x3);
      l4.x = f2bf(x0-bfu2f(h4.x)); l4.y = f2bf(x1-bfu2f(h4.y));
      l4.z = f2bf(x2-bfu2f(h4.z)); l4.w = f2bf(x3-bfu2f(h4.w));
      *(ushort4*)&W2Th[wo] = h4;
      *(ushort4*)&W2Tl[wo] = l4;
      float w30 = x0 * __expf(Le - __shfl(gv, t4+0));
      float w31 = x1 * __expf(Le - __shfl(gv, t4+1));
      float w32 = x2 * __expf(Le - __shfl(gv, t4+2));
      float w33 = x3 * __expf(Le - __shfl(gv, t4+3));
      ushort4 h3, l3;
      h3.x = f2bf(w30); h3.y = f2bf(w31); h3.z = f2bf(w32); h3.w = f2bf(w33);
      l3.x = f2bf(w30-bfu2f(h3.x)); l3.y = f2bf(w31-bfu2f(h3.y));
      l3.z = f2bf(w32-bfu2f(h3.z)); l3.w = f2bf(w33-bfu2f(h3.w));
      *(ushort4*)&W3Th[wo] = h3;
      *(ushort4*)&W3Tl[wo] = l3;
    }
    __syncthreads();

    if (isQ) {
      f32x4 oa = (f32x4){0.f,0.f,0.f,0.f};
      f32x4 ob2 = (f32x4){0.f,0.f,0.f,0.f};
      const int b0 = v16*64 + ((quad ^ vx) << 3);
      const int b1 = v16*64 + (((4 + quad) ^ vx) << 3);
      bf16x8 w0h = *(const bf16x8*)&W2Th[b0];
      bf16x8 w0l = *(const bf16x8*)&W2Tl[b0];
      bf16x8 w1h = *(const bf16x8*)&W2Th[b1];
      bf16x8 w1l = *(const bf16x8*)&W2Tl[b1];
      oa  = MFMA16(bfh0, w0h, oa);
      ob2 = MFMA16(bfh0, w0l, ob2);
      ob2 = MFMA16(bfl0, w0h, ob2);
      oa  = MFMA16(bfh1, w1h, oa);
      ob2 = MFMA16(bfh1, w1l, ob2);
      ob2 = MFMA16(bfl1, w1h, ob2);
      #pragma unroll
      for (int r = 0; r < 4; ++r) {
        const int t = t4 + r;
        float ga = __expf(__shfl(gv, t));
        og[(size_t)(t0 + t)*128 + v16] = fmaf(ga, qacc[r], oa[r] + ob2[r]);
      }
    }

    if (ch != 15) {
      float gC = __expf(__shfl(gv, 63));
      sreg[0] *= gC; sreg[1] *= gC; sreg[2] *= gC; sreg[3] *= gC;
      f32x4 s2 = (f32x4){0.f,0.f,0.f,0.f};
      #pragma unroll
      for (int ks = 0; ks < 2; ++ks) {
        const int u = 4*ks + quad;
        const int tbase = u * 8;
        bf16x8 ahi, alo;
        #pragma unroll
        for (int j = 0; j < 8; ++j) {
          const int ad = (tbase + j)*128 + ((k8 ^ j) << 3) + k7;
          ahi[j] = *(const __bf16*)&KhiL[cur][ad];
          alo[j] = *(const __bf16*)&KloL[cur][ad];
        }
        const int bo = v16*64 + ((u ^ vx) << 3);
        bf16x8 bhi = *(const bf16x8*)&W3Th[bo];
        bf16x8 blo = *(const bf16x8*)&W3Tl[bo];
        sreg = MFMA16(ahi, bhi, sreg);
        s2   = MFMA16(ahi, blo, s2);
        s2   = MFMA16(alo, bhi, s2);
      }
      sreg[0] += s2[0]; sreg[1] += s2[1]; sreg[2] += s2[2]; sreg[3] += s2[3];
      const int so = v16*128 + ((kr8 ^ vx) << 3) + kq4;
      ushort4 h4, l4;
      h4.x = f2bf(sreg[0]); h4.y = f2bf(sreg[1]);
      h4.z = f2bf(sreg[2]); h4.w = f2bf(sreg[3]);
      l4.x = f2bf(sreg[0]-bfu2f(h4.x)); l4.y = f2bf(sreg[1]-bfu2f(h4.y));
      l4.z = f2bf(sreg[2]-bfu2f(h4.z)); l4.w = f2bf(sreg[3]-bfu2f(h4.w));
      *(ushort4*)&S0h[so] = h4;
      *(ushort4*)&S0l[so] = l4;
    }
  }
}

// rmsnorm(o)*norm_w*silu(z) -> bf16 og; z bf16.
// 256 threads = 4 rows/block.
__global__ __launch_bounds__(256) void gnorm_kernel(
    const float* __restrict__ ob, const unsigned short* __restrict__ zbb,
    const float* __restrict__ norm_w, unsigned short* __restrict__ og) {
  const int tid = threadIdx.x;
  const int idx = blockIdx.x * 4 + (tid >> 6);
  const int lane = tid & 63;
  const int t = idx & 1023;
  const int bh = idx >> 10;
  const int b = bh >> 3;
  const int h = bh & 7;
  const float* o = ob + ((size_t)bh*T_ + t)*128;
  float2 ov = *(const float2*)(o + lane*2);
  float ss = fmaf(ov.x, ov.x, ov.y*ov.y);
  #pragma unroll
  for (int m=1; m<64; m<<=1) ss += __shfl_xor(ss, m);
  float inv = rsqrtf(ss*(1.f/128.f) + 1e-6f);
  size_t zoff = ((size_t)(b*T_+t))*1024 + (size_t)h*128 + lane*2;
  ushort2 zv = *(const ushort2*)(zbb + zoff);
  float z0 = bfu2f(zv.x), z1 = bfu2f(zv.y);
  float n0 = norm_w[lane*2], n1 = norm_w[lane*2+1];
  float r0 = ov.x*inv*n0 * z0/(1.f+expf(-z0));
  float r1 = ov.y*inv*n1 * z1/(1.f+expf(-z1));
  ushort2 ot;
  ot.x = f2bf(r0); ot.y = f2bf(r1);
  *(ushort2*)(og + zoff) = ot;
}

extern "C" void kernel_launch(void* const* d_in, const int* in_sizes, int n_in,
                              void* d_out, int out_size, void* d_ws, size_t ws_size,
                              hipStream_t stream) {
  const float* hs     = (const float*)d_in[0];
  const float* qkv_w  = (const float*)d_in[1];
  const float* z_w    = (const float*)d_in[2];
  const float* b_w    = (const float*)d_in[3];
  const float* a_w    = (const float*)d_in[4];
  const float* conv_w = (const float*)d_in[5];
  const float* dt_bias= (const float*)d_in[6];
  const float* A_log  = (const float*)d_in[7];
  const float* norm_w = (const float*)d_in[8];
  const float* out_w  = (const float*)d_in[9];
  float* out = (float*)d_out;

  char* wsp = (char*)d_ws;
  size_t off = 0;
  auto give = [&](size_t bytes)->char*{
    char* p = wsp + off; off += (bytes + 255) & ~(size_t)255; return p;
  };
  char* big    = give((size_t)MROWS*CONV_DIM_*4);            // 48 MB: k/q hi/lo + v
  unsigned short* zbuf = (unsigned short*)give((size_t)MROWS*1024*2);  // 8 MB
  unsigned short* outw_bf = (unsigned short*)give((size_t)HID_*1024*2); // 2 MB
  char* bufA   = give((size_t)32*T_*128*4);                  // 16 MB
  char* bufB   = give((size_t)32*T_*128*4);                  // 16 MB
  char* bufC   = give((size_t)32*T_*128*4);                  // 16 MB
  float* gbuf  = (float*)give((size_t)32*T_*4);
  float* beta  = (float*)give((size_t)32*T_*4);

  // big (48 MB): fused GEMM+conv outputs
  unsigned short* khi = (unsigned short*)big;                     // 8 MB
  unsigned short* klo = khi + (size_t)4*1024*1024;                // 8 MB
  unsigned short* qhi = klo + (size_t)4*1024*1024;                // 8 MB
  unsigned short* qlo = qhi + (size_t)4*1024*1024;                // 8 MB
  float* vdat = (float*)(qlo + (size_t)4*1024*1024);              // 16 MB
  // bufA: wz_bf [0,2MB) -> Blo [2,6MB) -> og [6,10MB); edge [10,12.25MB)
  unsigned short* wz_bf = (unsigned short*)bufA;
  unsigned short* Blo_g = (unsigned short*)bufA + (size_t)1024*1024;
  unsigned short* og    = (unsigned short*)bufA + (size_t)3*1024*1024;
  float* edge           = (float*)(bufA + (size_t)10*1024*1024);  // 2.25 MB
  // bufB: hs_hi/lo [0,16MB) -> Thi [0,4) Tlo [4,8) Bhi [8,12)
  unsigned short* hs_hi = (unsigned short*)bufB;
  unsigned short* hs_lo = hs_hi + (size_t)MROWS*HID_;
  unsigned short* Thi_g = (unsigned short*)bufB;
  unsigned short* Tlo_g = Thi_g + (size_t)512*4096;
  unsigned short* Bhi_g = Tlo_g + (size_t)512*4096;
  // bufC: wc_hi/lo [0,12.6MB) -> ob [0,16MB)
  unsigned short* wc_hi = (unsigned short*)bufC;
  unsigned short* wc_lo = wc_hi + (size_t)CONV_DIM_*HID_;
  float* ob = (float*)bufC;

  prep_kernel<<<dim3(5120 + MROWS/2), 256, 0, stream>>>(
      qkv_w, z_w, out_w, wc_hi, wc_lo, wz_bf, outw_bf,
      hs, b_w, a_w, dt_bias, A_log, gbuf, beta, hs_hi, hs_lo);
  gemm_split_conv_kernel<<<dim3(32, MROWS/128), 256, 0, stream>>>(
      hs_hi, hs_lo, wc_hi, wc_lo, wz_bf, conv_w, qhi, qlo, khi, klo, vdat, edge, zbuf);
  conv_fix_kernel<<<dim3(32*24), dim3(128), 0, stream>>>(
      edge, conv_w, qhi, qlo, khi, klo, vdat);
  scan_ab_kernel<<<dim3(512), dim3(256), 0, stream>>>(
      qhi, qlo, khi, klo, gbuf, beta, Thi_g, Tlo_g, Bhi_g, Blo_g);
  scan_seq_kernel<<<dim3(256), dim3(512), 0, stream>>>(
      khi, klo, qhi, qlo, vdat, gbuf, beta, Thi_g, Tlo_g, Bhi_g, Blo_g, ob);
  gnorm_kernel<<<dim3(32*T_/4), dim3(256), 0, stream>>>(ob, zbuf, norm_w, og);
  gemm_mfma_kernel<0><<<dim3(1024/128, MROWS/128), 256, 0, stream>>>(og, outw_bf, out, MROWS, 1024, HID_);
}

// Round 16
// 329.820 us; speedup vs baseline: 1.0365x; 1.0102x over previous
//
#include <hip/hip_runtime.h>

#define B_ 4
#define T_ 1024
#define HID_ 1024
#define H_ 8
#define CONV_DIM_ 3072
#define MROWS (B_*T_)

typedef __bf16 bf16x8 __attribute__((ext_vector_type(8)));
typedef float f32x4 __attribute__((ext_vector_type(4)));

#define MFMA16(a,b,c) __builtin_amdgcn_mfma_f32_16x16x32_bf16((a),(b),(c),0,0,0)

static __device__ __forceinline__ unsigned short f2bf(float f) {
  unsigned u = __float_as_uint(f);
  unsigned r = u + 0x7fffu + ((u >> 16) & 1u);   // RNE
  return (unsigned short)(r >> 16);
}
static __device__ __forceinline__ float bfu2f(unsigned short v) {
  return __uint_as_float(((unsigned)v) << 16);
}
static __device__ __forceinline__ float4 recon4(ushort4 h, ushort4 l) {
  float4 r;
  r.x = bfu2f(h.x) + bfu2f(l.x);
  r.y = bfu2f(h.y) + bfu2f(l.y);
  r.z = bfu2f(h.z) + bfu2f(l.z);
  r.w = bfu2f(h.w) + bfu2f(l.w);
  return r;
}

// async global->LDS 16B. LDS dest must be wave-uniform base + lane*16 (m104/m108).
static __device__ __forceinline__ void gld16(void* lds, const void* g) {
  __builtin_amdgcn_global_load_lds(
      (const __attribute__((address_space(1))) unsigned int*)g,
      (__attribute__((address_space(3))) unsigned int*)lds, 16, 0, 0);
}

// Merged front-end: weight conversions AND bb/aa projections in ONE dispatch.
//   bid < 3072          : qkv_w -> hi/lo split
//   3072 <= bid < 4096  : z_w -> bf16
//   4096 <= bid < 5120  : out_w -> bf16
//   bid >= 5120         : proj_ba path, 2 rows per block (256 thr = 2x128)
__global__ __launch_bounds__(256) void prep_kernel(
    const float* __restrict__ qkv_w, const float* __restrict__ z_w,
    const float* __restrict__ out_w,
    unsigned short* __restrict__ wc_hi, unsigned short* __restrict__ wc_lo,
    unsigned short* __restrict__ wz_bf, unsigned short* __restrict__ outw_bf,
    const float* __restrict__ hs, const float* __restrict__ b_w,
    const float* __restrict__ a_w, const float* __restrict__ dt_bias,
    const float* __restrict__ A_log,
    float* __restrict__ gout, float* __restrict__ beta,
    unsigned short* __restrict__ hs_hi, unsigned short* __restrict__ hs_lo) {
  const int bid = blockIdx.x;
  const int tid = threadIdx.x;
  if (bid < 3072) {
    int i = (bid * 256 + tid) * 4;
    float4 v = *(const float4*)(qkv_w + i);
    ushort4 h, l;
    h.x = f2bf(v.x); h.y = f2bf(v.y); h.z = f2bf(v.z); h.w = f2bf(v.w);
    l.x = f2bf(v.x - bfu2f(h.x));
    l.y = f2bf(v.y - bfu2f(h.y));
    l.z = f2bf(v.z - bfu2f(h.z));
    l.w = f2bf(v.w - bfu2f(h.w));
    *(ushort4*)(wc_hi + i) = h;
    *(ushort4*)(wc_lo + i) = l;
    return;
  }
  if (bid < 5120) {
    const bool isZ = (bid < 4096);
    const float* src = isZ ? z_w : out_w;
    unsigned short* dst = isZ ? wz_bf : outw_bf;
    int i = (((bid - (isZ ? 3072 : 4096)) * 256) + tid) * 4;
    float4 v = *(const float4*)(src + i);
    ushort4 o;
    o.x = f2bf(v.x); o.y = f2bf(v.y); o.z = f2bf(v.z); o.w = f2bf(v.w);
    *(ushort4*)(dst + i) = o;
    return;
  }
  // ---- proj_ba path: 2 rows per block, 128 threads each
  const int pb = bid - 5120;
  const int ltid = tid & 127;
  const int bt = pb * 2 + (tid >> 7);
  const int b = bt >> 10;
  const int t = bt & 1023;
  const int grp = ltid >> 3;
  const int l8 = ltid & 7;
  const int h = grp & 7;
  const bool isA = grp >= 8;
  const float* w = (isA ? a_w : b_w) + (size_t)h * HID_;
  const float* x = hs + (size_t)bt * HID_;
  // coalesced hs -> bf16 hi/lo emit: 128 threads x 8 elems per row
  {
    const int e = ltid * 8;
    float4 xv0 = *(const float4*)(x + e);
    float4 xv1 = *(const float4*)(x + e + 4);
    ushort4 h0, l0, h1, l1;
    h0.x = f2bf(xv0.x); h0.y = f2bf(xv0.y); h0.z = f2bf(xv0.z); h0.w = f2bf(xv0.w);
    l0.x = f2bf(xv0.x - bfu2f(h0.x)); l0.y = f2bf(xv0.y - bfu2f(h0.y));
    l0.z = f2bf(xv0.z - bfu2f(h0.z)); l0.w = f2bf(xv0.w - bfu2f(h0.w));
    h1.x = f2bf(xv1.x); h1.y = f2bf(xv1.y); h1.z = f2bf(xv1.z); h1.w = f2bf(xv1.w);
    l1.x = f2bf(xv1.x - bfu2f(h1.x)); l1.y = f2bf(xv1.y - bfu2f(h1.y));
    l1.z = f2bf(xv1.z - bfu2f(h1.z)); l1.w = f2bf(xv1.w - bfu2f(h1.w));
    unsigned short* hho = hs_hi + (size_t)bt * HID_ + e;
    unsigned short* hlo = hs_lo + (size_t)bt * HID_ + e;
    *(ushort4*)hho = h0;       *(ushort4*)hlo = l0;
    *(ushort4*)(hho + 4) = h1; *(ushort4*)(hlo + 4) = l1;
  }
  float s = 0.f;
  for (int e = l8*4; e < HID_; e += 32){
    float4 xv = *(const float4*)(x + e);
    float4 wv = *(const float4*)(w + e);
    s = fmaf(xv.x, wv.x, s);
    s = fmaf(xv.y, wv.y, s);
    s = fmaf(xv.z, wv.z, s);
    s = fmaf(xv.w, wv.w, s);
  }
  s += __shfl_xor(s,1); s += __shfl_xor(s,2); s += __shfl_xor(s,4);
  if (l8 == 0) {
    size_t o = ((size_t)(b*H_ + h))*T_ + t;
    if (!isA) {
      beta[o] = 1.f/(1.f+expf(-s));
    } else {
      float xx = s + dt_bias[h];
      float sp = fmaxf(xx,0.f) + log1pf(expf(-fabsf(xx)));   // softplus
      gout[o] = -expf(A_log[h]) * sp;                        // g = log(alpha)
    }
  }
}

// Single-pass bf16 MFMA GEMM: C[M,N] = A[M,K] * W[N,K]^T. 128x128 tile, BK=64
// (two 32-K sub-tiles per barrier-pair: halves barrier count; at 256 blocks =
// 1 block/CU this loop is latency/barrier-bound, not staging-bound).
template<int OUT_BF16>
__global__ __launch_bounds__(256) void gemm_mfma_kernel(
    const unsigned short* __restrict__ A, const unsigned short* __restrict__ W,
    void* __restrict__ Cv, int M, int N, int K) {
  __shared__ __align__(16) unsigned short lA[2*128*32];
  __shared__ __align__(16) unsigned short lB[2*128*32];
  const int tid  = threadIdx.x;
  const int lane = tid & 63;
  const int wv   = tid >> 6;
  const int wm   = (wv >> 1) * 64;
  const int wn   = (wv & 1) * 64;
  const int m16  = lane & 15;
  const int quad = lane >> 4;
  const int bm = blockIdx.y * 128;
  const int bn = blockIdx.x * 128;

  f32x4 acc[4][4];
  #pragma unroll
  for (int i = 0; i < 4; ++i)
    #pragma unroll
    for (int j = 0; j < 4; ++j)
      acc[i][j] = (f32x4){0.f, 0.f, 0.f, 0.f};

  const int r0 = tid >> 2, c0 = tid & 3;
  const int r1 = r0 + 64;
  const int g0 = (c0 ^ (r0 & 3)) * 8;
  const int g1 = (c0 ^ (r1 & 3)) * 8;
  const unsigned short* Ar0 = A + (size_t)(bm + r0) * K + g0;
  const unsigned short* Ar1 = A + (size_t)(bm + r1) * K + g1;
  const unsigned short* Wr0 = W + (size_t)(bn + r0) * K + g0;
  const unsigned short* Wr1 = W + (size_t)(bn + r1) * K + g1;
  const int s0 = tid * 8, s1 = (tid + 256) * 8;

  int offA[4], offB[4];
  #pragma unroll
  for (int i = 0; i < 4; ++i) {
    int ra = wm + i * 16 + m16;
    offA[i] = ra * 32 + (quad ^ (ra & 3)) * 8;
    int rb = wn + i * 16 + m16;
    offB[i] = rb * 32 + (quad ^ (rb & 3)) * 8;
  }

  for (int k0 = 0; k0 < K; k0 += 64) {
    gld16(&lA[s0],        Ar0 + k0);
    gld16(&lA[s1],        Ar1 + k0);
    gld16(&lA[4096 + s0], Ar0 + k0 + 32);
    gld16(&lA[4096 + s1], Ar1 + k0 + 32);
    gld16(&lB[s0],        Wr0 + k0);
    gld16(&lB[s1],        Wr1 + k0);
    gld16(&lB[4096 + s0], Wr0 + k0 + 32);
    gld16(&lB[4096 + s1], Wr1 + k0 + 32);
    __syncthreads();
    #pragma unroll
    for (int sub = 0; sub < 2; ++sub) {
      const int sb = sub * 4096;
      bf16x8 af[4], bfr[4];
      #pragma unroll
      for (int i = 0; i < 4; ++i) {
        af[i]  = *(const bf16x8*)&lA[sb + offA[i]];
        bfr[i] = *(const bf16x8*)&lB[sb + offB[i]];
      }
      #pragma unroll
      for (int mi = 0; mi < 4; ++mi)
        #pragma unroll
        for (int ni = 0; ni < 4; ++ni)
          acc[mi][ni] = MFMA16(af[mi], bfr[ni], acc[mi][ni]);
    }
    __syncthreads();
  }

  #pragma unroll
  for (int mi = 0; mi < 4; ++mi) {
    #pragma unroll
    for (int r = 0; r < 4; ++r) {
      size_t row = (size_t)(bm + wm + mi * 16 + quad * 4 + r);
      #pragma unroll
      for (int ni = 0; ni < 4; ++ni) {
        int col = bn + wn + ni * 16 + m16;
        float val = acc[mi][ni][r];
        if (OUT_BF16) ((unsigned short*)Cv)[row * N + col] = f2bf(val);
        else          ((float*)Cv)[row * N + col] = val;
      }
    }
  }
}

// Fused: split-precision MFMA GEMM (mixed = hs.qkv_w^T, 3 products) + causal
// depthwise conv (K=4) epilogue, PLUS merged z-projection on blocks x>=24.
// NOTE (round-11 lesson): the Alo.Whi term is REQUIRED — dropping it gave
// absmax 0.18 (the scan recurrence amplifies q/k operand error ~100x).
// z path runs BK=64 (2 sub-tiles per barrier, 4 tile-slots = the full 32KB
// staging region) — z has only 16 MFMA/barrier-pair and is barrier-bound.
// Epilogue: two 64-row half-tiles through [64][132] fp32 LDS (35328B total).
__global__ __launch_bounds__(256) void gemm_split_conv_kernel(
    const unsigned short* __restrict__ Ahi, const unsigned short* __restrict__ Alo,
    const unsigned short* __restrict__ Whi, const unsigned short* __restrict__ Wlo,
    const unsigned short* __restrict__ Wz,
    const float* __restrict__ conv_w,
    unsigned short* __restrict__ qhi, unsigned short* __restrict__ qlo,
    unsigned short* __restrict__ khi, unsigned short* __restrict__ klo,
    float* __restrict__ vb, float* __restrict__ edge,
    unsigned short* __restrict__ zbuf) {
  __shared__ __align__(16) unsigned char ldsraw[64*132*4 + 3*128*4];
  unsigned short* lAh = (unsigned short*)ldsraw;
  unsigned short* lAl = lAh + 128*32;
  unsigned short* lBh = lAl + 128*32;
  unsigned short* lBl = lBh + 128*32;
  float* smX2  = (float*)ldsraw;
  float* carry = (float*)(ldsraw + 64*132*4);

  const int tid  = threadIdx.x;
  const int lane = tid & 63;
  const int wv   = tid >> 6;
  const int wm   = (wv >> 1) * 64;
  const int wn   = (wv & 1) * 64;
  const int m16  = lane & 15;
  const int quad = lane >> 4;
  const int bm = blockIdx.y * 128;

  f32x4 acc[4][4];
  #pragma unroll
  for (int i = 0; i < 4; ++i)
    #pragma unroll
    for (int j = 0; j < 4; ++j)
      acc[i][j] = (f32x4){0.f, 0.f, 0.f, 0.f};

  const int r0 = tid >> 2, c0 = tid & 3;
  const int r1 = r0 + 64;
  const int g0 = (c0 ^ (r0 & 3)) * 8;
  const int g1 = (c0 ^ (r1 & 3)) * 8;
  const size_t oA0 = (size_t)(bm + r0) * 1024 + g0;
  const size_t oA1 = (size_t)(bm + r1) * 1024 + g1;
  const int s0 = tid * 8, s1 = (tid + 256) * 8;

  int offA[4], offB[4];
  #pragma unroll
  for (int i = 0; i < 4; ++i) {
    int ra = wm + i * 16 + m16;
    offA[i] = ra * 32 + (quad ^ (ra & 3)) * 8;
    int rb = wn + i * 16 + m16;
    offB[i] = rb * 32 + (quad ^ (rb & 3)) * 8;
  }

  // ---- z path (blocks x>=24): z = hs_hi . z_w^T, single product, bf16 out.
  // BK=64: A sub-tiles at lAh[0]/lAh[4096], B sub-tiles at lAh[8192]/lAh[12288]
  // (reuses the whole 4-tile staging region; qkv tile pointers unused here).
  if (blockIdx.x >= 24) {
    unsigned short* Z = (unsigned short*)ldsraw;
    const int bn = (blockIdx.x - 24) * 128;
    const size_t oBz0 = (size_t)(bn + r0) * 1024 + g0;
    const size_t oBz1 = (size_t)(bn + r1) * 1024 + g1;
    for (int k0 = 0; k0 < 1024; k0 += 64) {
      gld16(&Z[s0],         Ahi + oA0 + k0);
      gld16(&Z[s1],         Ahi + oA1 + k0);
      gld16(&Z[4096 + s0],  Ahi + oA0 + k0 + 32);
      gld16(&Z[4096 + s1],  Ahi + oA1 + k0 + 32);
      gld16(&Z[8192 + s0],  Wz + oBz0 + k0);
      gld16(&Z[8192 + s1],  Wz + oBz1 + k0);
      gld16(&Z[12288 + s0], Wz + oBz0 + k0 + 32);
      gld16(&Z[12288 + s1], Wz + oBz1 + k0 + 32);
      __syncthreads();
      #pragma unroll
      for (int sub = 0; sub < 2; ++sub) {
        const int ab = sub * 4096;
        const int bb = 8192 + sub * 4096;
        bf16x8 af[4], bfr[4];
        #pragma unroll
        for (int i = 0; i < 4; ++i) {
          af[i]  = *(const bf16x8*)&Z[ab + offA[i]];
          bfr[i] = *(const bf16x8*)&Z[bb + offB[i]];
        }
        #pragma unroll
        for (int mi = 0; mi < 4; ++mi)
          #pragma unroll
          for (int ni = 0; ni < 4; ++ni)
            acc[mi][ni] = MFMA16(af[mi], bfr[ni], acc[mi][ni]);
      }
      __syncthreads();
    }
    #pragma unroll
    for (int mi = 0; mi < 4; ++mi) {
      #pragma unroll
      for (int r = 0; r < 4; ++r) {
        size_t row = (size_t)(bm + wm + mi * 16 + quad * 4 + r);
        #pragma unroll
        for (int ni = 0; ni < 4; ++ni)
          zbuf[row * 1024 + bn + wn + ni * 16 + m16] = f2bf(acc[mi][ni][r]);
      }
    }
    return;
  }

  // ---- qkv path (blocks x<24): BK=32, 3-product split (unchanged)
  const int bn = blockIdx.x * 128;
  const size_t oB0 = (size_t)(bn + r0) * 1024 + g0;
  const size_t oB1 = (size_t)(bn + r1) * 1024 + g1;

  for (int k0 = 0; k0 < 1024; k0 += 32) {
    gld16(&lAh[s0], Ahi + oA0 + k0);
    gld16(&lAh[s1], Ahi + oA1 + k0);
    gld16(&lAl[s0], Alo + oA0 + k0);
    gld16(&lAl[s1], Alo + oA1 + k0);
    gld16(&lBh[s0], Whi + oB0 + k0);
    gld16(&lBh[s1], Whi + oB1 + k0);
    gld16(&lBl[s0], Wlo + oB0 + k0);
    gld16(&lBl[s1], Wlo + oB1 + k0);
    __syncthreads();
    bf16x8 afh[4], bfh[4];
    #pragma unroll
    for (int i = 0; i < 4; ++i) {
      afh[i] = *(const bf16x8*)&lAh[offA[i]];
      bfh[i] = *(const bf16x8*)&lBh[offB[i]];
    }
    #pragma unroll
    for (int mi = 0; mi < 4; ++mi)
      #pragma unroll
      for (int ni = 0; ni < 4; ++ni)
        acc[mi][ni] = MFMA16(afh[mi], bfh[ni], acc[mi][ni]);
    {
      bf16x8 bfl[4];
      #pragma unroll
      for (int i = 0; i < 4; ++i) bfl[i] = *(const bf16x8*)&lBl[offB[i]];
      #pragma unroll
      for (int mi = 0; mi < 4; ++mi)
        #pragma unroll
        for (int ni = 0; ni < 4; ++ni)
          acc[mi][ni] = MFMA16(afh[mi], bfl[ni], acc[mi][ni]);
    }
    {
      bf16x8 afl[4];
      #pragma unroll
      for (int i = 0; i < 4; ++i) afl[i] = *(const bf16x8*)&lAl[offA[i]];
      #pragma unroll
      for (int mi = 0; mi < 4; ++mi)
        #pragma unroll
        for (int ni = 0; ni < 4; ++ni)
          acc[mi][ni] = MFMA16(afl[mi], bfh[ni], acc[mi][ni]);
    }
    __syncthreads();   // last iter: all staging reads done -> smX2 alias safe
  }

  // ---- epilogue: two 64-row half-tiles
  const int bi = blockIdx.y;
  const int c  = tid & 127;
  const int rh = tid >> 7;
  const int cg = bn + c;
  const int part = cg >> 10;         // block-uniform
  const int hh = (cg & 1023) >> 7;   // block-uniform
  const int b = bm >> 10;
  const int tloc0 = bm & 1023;
  float4 w4 = *(const float4*)(conv_w + cg * 4);
  size_t rowb = ((size_t)(b * H_ + hh)) * T_;
  unsigned short* dh = (part == 0) ? qhi : khi;
  unsigned short* dl = (part == 0) ? qlo : klo;

  #pragma unroll
  for (int half = 0; half < 2; ++half) {
    if (half == 1) __syncthreads();   // half-0 conv reads + carry save done
    if ((wv >> 1) == half) {
      #pragma unroll
      for (int mi = 0; mi < 4; ++mi)
        #pragma unroll
        for (int r = 0; r < 4; ++r) {
          int row = mi * 16 + quad * 4 + r;
          #pragma unroll
          for (int ni = 0; ni < 4; ++ni)
            smX2[row * 132 + wn + ni * 16 + m16] = acc[mi][ni][r];
        }
    }
    __syncthreads();
    // edge spill + (half 0) carry save — 384 items via e*256+tid (256 threads)
    if (half == 0) {
      #pragma unroll
      for (int e = 0; e < 2; ++e) {
        int idx = e * 256 + tid;
        int r = idx >> 7, cc = idx & 127;
        if (r < 3) {
          edge[((size_t)bi*6 + 3 + r)*3072 + bn + cc] = smX2[r*132 + cc];
          carry[r*128 + cc] = smX2[(61+r)*132 + cc];
        }
      }
    } else {
      if (bi < 31) {
        #pragma unroll
        for (int e = 0; e < 2; ++e) {
          int idx = e * 256 + tid;
          int r = idx >> 7, cc = idx & 127;
          if (r < 3)
            edge[((size_t)(bi+1)*6 + r)*3072 + bn + cc] = smX2[(61+r)*132 + cc];
        }
      }
    }
    // conv: 2 threads/col, 32 t-steps each
    {
      const int tb0 = rh * 32;
      float x0, x1, x2;
      if (tb0 >= 3) {
        x0 = smX2[(tb0-3)*132 + c];
        x1 = smX2[(tb0-2)*132 + c];
        x2 = smX2[(tb0-1)*132 + c];
      } else {  // tb0 == 0
        if (half == 0) { x0 = 0.f; x1 = 0.f; x2 = 0.f; }
        else { x0 = carry[0*128 + c]; x1 = carry[1*128 + c]; x2 = carry[2*128 + c]; }
      }
      for (int tt = 0; tt < 32; ++tt) {
        const int t = tb0 + tt;
        float x3 = smX2[t*132 + c];
        float s = fmaf(w4.x, x0, fmaf(w4.y, x1, fmaf(w4.z, x2, w4.w * x3)));
        x0 = x1; x1 = x2; x2 = x3;
        const int tg = tloc0 + half*64 + t;
        if (part == 2) {
          vb[(rowb + tg) * 128 + c] = s;
        } else {
          int sw = (((c >> 3) ^ (tg & 7)) << 3) + (c & 7);
          unsigned short hv = f2bf(s);
          dh[(rowb + tg) * 128 + sw] = hv;
          dl[(rowb + tg) * 128 + sw] = f2bf(s - bfu2f(hv));
        }
      }
    }
  }
}

// Boundary fixup (trivial): 6 mixed rows come straight from the edge buffer.
__global__ __launch_bounds__(128) void conv_fix_kernel(
    const float* __restrict__ edge, const float* __restrict__ conv_w,
    unsigned short* __restrict__ qhi, unsigned short* __restrict__ qlo,
    unsigned short* __restrict__ khi, unsigned short* __restrict__ klo,
    float* __restrict__ vb) {
  const int bi = blockIdx.x / 24;
  const int cb = blockIdx.x % 24;
  const int bm = bi * 128, n0 = cb * 128;
  const int b = bm >> 10, tloc = bm & 1023;
  const int c = threadIdx.x;
  const int cg = n0 + c;
  float m[6];
  #pragma unroll
  for (int j = 0; j < 6; ++j)
    m[j] = edge[((size_t)bi*6 + j)*3072 + cg];
  if (tloc == 0) { m[0] = 0.f; m[1] = 0.f; m[2] = 0.f; }
  const int part = cg >> 10;
  const int hh = (cg & 1023) >> 7;
  float4 w4 = *(const float4*)(conv_w + cg * 4);
  size_t rowb = ((size_t)(b * H_ + hh)) * T_;
  unsigned short* dh = (part == 0) ? qhi : khi;
  unsigned short* dl = (part == 0) ? qlo : klo;
  #pragma unroll
  for (int jo = 0; jo < 3; ++jo) {
    float s = fmaf(w4.x, m[jo], fmaf(w4.y, m[jo+1],
              fmaf(w4.z, m[jo+2], w4.w * m[jo+3])));
    const int tg = tloc + jo;
    if (part == 2) {
      vb[(rowb + tg) * 128 + c] = s;
    } else {
      int sw = (((c >> 3) ^ (tg & 7)) << 3) + (c & 7);
      unsigned short hv = f2bf(s);
      dh[(rowb + tg) * 128 + sw] = hv;
      dl[(rowb + tg) * 128 + sw] = f2bf(s - bfu2f(hv));
    }
  }
}

// Parallel precompute: 512 blocks = (bh, chunk). MFMA version.
// T = (I+A)^-1 (unit lower), B = incl-lower decayed QK^T.
__global__ __launch_bounds__(256) void scan_ab_kernel(
    const unsigned short* __restrict__ qhi_g, const unsigned short* __restrict__ qlo_g,
    const unsigned short* __restrict__ khi_g, const unsigned short* __restrict__ klo_g,
    const float* __restrict__ gbuf, const float* __restrict__ bbuf,
    unsigned short* __restrict__ Thi_g, unsigned short* __restrict__ Tlo_g,
    unsigned short* __restrict__ Bhi_g, unsigned short* __restrict__ Blo_g) {
  const int blk = blockIdx.x;
  const int bh = blk >> 4;
  const int ch = blk & 15;
  const int t0 = ch * 64;
  const int tid = threadIdx.x;
  const int wvb = tid >> 6;          // wave = output row-block
  const int lane = tid & 63;
  const int v16 = lane & 15;
  const int quad = lane >> 4;
  __shared__ float sAA[64][68];
  __shared__ float lL[64];
  __shared__ float bL[64];
  unsigned short* Tho = Thi_g + (size_t)blk*4096;
  unsigned short* Tlo = Tlo_g + (size_t)blk*4096;
  unsigned short* Bho = Bhi_g + (size_t)blk*4096;
  unsigned short* Blo = Blo_g + (size_t)blk*4096;
  const unsigned short* kh  = khi_g + (size_t)bh*131072 + (size_t)t0*128;
  const unsigned short* klp = klo_g + (size_t)bh*131072 + (size_t)t0*128;
  const unsigned short* qh  = qhi_g + (size_t)bh*131072 + (size_t)t0*128;
  const unsigned short* qlp = qlo_g + (size_t)bh*131072 + (size_t)t0*128;

  if (tid < 64) {
    float x = gbuf[(size_t)bh*T_ + t0 + tid];
    #pragma unroll
    for (int o = 1; o < 64; o <<= 1) {
      float y = __shfl_up(x, o);
      if (tid >= o) x += y;
    }
    lL[tid] = x;
    bL[tid] = bbuf[(size_t)bh*T_ + t0 + tid];
  }

  const int ar = wvb*16 + v16;
  const int arx = ar & 7;
  bf16x8 kAh[4], kAl[4], qAh[4], qAl[4];
  #pragma unroll
  for (int ks = 0; ks < 4; ++ks) {
    const int u = 4*ks + quad;
    const int ao = ar*128 + ((u ^ arx) << 3);
    kAh[ks] = *(const bf16x8*)&kh[ao];
    kAl[ks] = *(const bf16x8*)&klp[ao];
    qAh[ks] = *(const bf16x8*)&qh[ao];
    qAl[ks] = *(const bf16x8*)&qlp[ao];
  }
  __syncthreads();   // lL/bL ready

  const int i0 = wvb*16 + quad*4;
  float biv[4], liv[4];
  #pragma unroll
  for (int r = 0; r < 4; ++r) { biv[r] = bL[i0+r]; liv[r] = lL[i0+r]; }

  #pragma unroll
  for (int cb = 0; cb < 4; ++cb) {
    const int j = cb*16 + v16;
    if (cb <= wvb) {
      const int rb = cb*16 + v16;
      const int rbx = rb & 7;
      f32x4 a1 = (f32x4){0.f,0.f,0.f,0.f}, a2 = (f32x4){0.f,0.f,0.f,0.f};
      f32x4 q1 = (f32x4){0.f,0.f,0.f,0.f}, q2 = (f32x4){0.f,0.f,0.f,0.f};
      #pragma unroll
      for (int ks = 0; ks < 4; ++ks) {
        const int u = 4*ks + quad;
        const int bo = rb*128 + ((u ^ rbx) << 3);
        bf16x8 bhv = *(const bf16x8*)&kh[bo];
        bf16x8 blv = *(const bf16x8*)&klp[bo];
        a1 = MFMA16(kAh[ks], bhv, a1);
        a2 = MFMA16(kAh[ks], blv, a2);
        a2 = MFMA16(kAl[ks], bhv, a2);
        q1 = MFMA16(qAh[ks], bhv, q1);
        q2 = MFMA16(qAh[ks], blv, q2);
        q2 = MFMA16(qAl[ks], bhv, q2);
      }
      float lj = lL[j];
      #pragma unroll
      for (int r = 0; r < 4; ++r) {
        const int i = i0 + r;
        float av = a1[r] + a2[r];
        float qv = q1[r] + q2[r];
        sAA[i][j] = (j < i) ? biv[r] * __expf(liv[r] - lj) * av : 0.f;
        float xq = (j <= i) ? __expf(liv[r] - lj) * qv : 0.f;
        unsigned short hv = f2bf(xq);
        int sidx = i*64 + (((j>>3) ^ (i&7)) << 3) + (j&7);
        Bho[sidx] = hv;
        Blo[sidx] = f2bf(xq - bfu2f(hv));
      }
    } else {
      #pragma unroll
      for (int r = 0; r < 4; ++r) {
        const int i = i0 + r;
        sAA[i][j] = 0.f;
        int sidx = i*64 + (((j>>3) ^ (i&7)) << 3) + (j&7);
        Bho[sidx] = 0;
        Blo[sidx] = 0;
      }
    }
  }
  __syncthreads();

  // invert (I+A): 4 waves x 16 cols, rows rr+4m per thread; wave-local chain
  {
    const int w = tid >> 6;
    const int ln = tid & 63;
    const int colc = w*16 + (ln & 15);
    const int rr = ln >> 4;
    float rh[16];
    #pragma unroll
    for (int m=0;m<16;++m) rh[m] = (rr + 4*m == colc) ? 1.f : 0.f;
    for (int j = 0; j < 63; ++j) {
      int src = ((j & 3) << 4) | (ln & 15);
      float wj = __shfl(rh[j >> 2], src);
      #pragma unroll
      for (int m=0;m<16;++m)
        rh[m] = fmaf(-sAA[rr + 4*m][j], wj, rh[m]);
    }
    #pragma unroll
    for (int m=0;m<16;++m) {
      int i2 = rr + 4*m;
      float x = rh[m];
      unsigned short hv = f2bf(x);
      int sidx = i2*64 + (((colc>>3) ^ (i2&7)) << 3) + (colc&7);
      Tho[sidx] = hv;
      Tlo[sidx] = f2bf(x - bfu2f(hv));
    }
  }
}

// Sequential chunked scan, 512 threads (8 waves), UT-transform, all-MFMA phases.
// XCD-aware block decode: bh = bid&31, sl = bid>>5.
__global__ __launch_bounds__(512) void scan_seq_kernel(
    const unsigned short* __restrict__ khi_g, const unsigned short* __restrict__ klo_g,
    const unsigned short* __restrict__ qhi_g, const unsigned short* __restrict__ qlo_g,
    const float* __restrict__ vb,
    const float* __restrict__ gbuf, const float* __restrict__ bbuf,
    const unsigned short* __restrict__ Thi_g, const unsigned short* __restrict__ Tlo_g,
    const unsigned short* __restrict__ Bhi_g, const unsigned short* __restrict__ Blo_g,
    float* __restrict__ ob) {
  const int bh = blockIdx.x & 31;
  const int sl = blockIdx.x >> 5;
  const int tid = threadIdx.x;
  const int wv = tid >> 6;
  const int lane = tid & 63;
  const int v16 = lane & 15;
  const int quad = lane >> 4;
  const int tb = (wv & 3) * 16;
  const bool isQ = (wv >= 4);
  const int vx = v16 & 7;

  __shared__ __align__(16) unsigned short KhiL[2][64*128];
  __shared__ __align__(16) unsigned short KloL[2][64*128];
  __shared__ __align__(16) unsigned short WTh[16*64],  WTl[16*64];
  __shared__ __align__(16) unsigned short W2Th[16*64], W2Tl[16*64];
  __shared__ __align__(16) unsigned short W3Th[16*64], W3Tl[16*64];
  __shared__ __align__(16) unsigned short S0h[16*128], S0l[16*128];

  const unsigned short* kh  = khi_g + (size_t)bh*131072;
  const unsigned short* klp = klo_g + (size_t)bh*131072;
  const unsigned short* qh  = qhi_g + (size_t)bh*131072;
  const unsigned short* qlp = qlo_g + (size_t)bh*131072;
  const float* vg = vb + (size_t)bh*T_*128 + sl*16;
  const float* gg = gbuf + (size_t)bh*T_;
  const float* beg = bbuf + (size_t)bh*T_;
  float* og = ob + (size_t)bh*T_*128 + sl*16;

  f32x4 sreg = (f32x4){0.f, 0.f, 0.f, 0.f};
  const int kk0 = wv*16 + v16;
  const int k8 = kk0 >> 3, k7 = kk0 & 7;
  const int kq4 = (quad & 1) * 4;
  const int kr8 = (wv*16 + quad*4) >> 3;

  gld16(&KhiL[0][tid*8],        kh + tid*8);
  gld16(&KhiL[0][4096 + tid*8], kh + 4096 + tid*8);
  gld16(&KloL[0][tid*8],        klp + tid*8);
  gld16(&KloL[0][4096 + tid*8], klp + 4096 + tid*8);

  for (int ch = 0; ch < 16; ++ch) {
    const int t0 = ch * 64;
    const int cur = ch & 1;
    __syncthreads();

    if (ch < 15) {
      const size_t co = (size_t)(t0 + 64) * 128;
      gld16(&KhiL[cur^1][tid*8],        kh + co + tid*8);
      gld16(&KhiL[cur^1][4096 + tid*8], kh + co + 4096 + tid*8);
      gld16(&KloL[cur^1][tid*8],        klp + co + tid*8);
      gld16(&KloL[cur^1][4096 + tid*8], klp + co + 4096 + tid*8);
    }

    float gv = gg[t0 + lane];
    #pragma unroll
    for (int o = 1; o < 64; o <<= 1) {
      float y = __shfl_up(gv, o);
      if (lane >= o) gv += y;
    }
    float bv = beg[t0 + lane];

    const int ar = tb + v16;
    const int arx = ar & 7;
    const size_t tbo = ((size_t)(bh*16 + ch)) * 4096;
    bf16x8 tfh0, tfh1, tfl0, tfl1;
    bf16x8 bfh0, bfh1, bfl0, bfl1;
    bf16x8 qfh[4], qfl[4];
    if (!isQ) {
      int a0 = ar*64 + ((quad ^ arx) << 3);
      int a1 = ar*64 + (((4 + quad) ^ arx) << 3);
      tfh0 = *(const bf16x8*)&Thi_g[tbo + a0];
      tfh1 = *(const bf16x8*)&Thi_g[tbo + a1];
      tfl0 = *(const bf16x8*)&Tlo_g[tbo + a0];
      tfl1 = *(const bf16x8*)&Tlo_g[tbo + a1];
    } else {
      int a0 = ar*64 + ((quad ^ arx) << 3);
      int a1 = ar*64 + (((4 + quad) ^ arx) << 3);
      bfh0 = *(const bf16x8*)&Bhi_g[tbo + a0];
      bfh1 = *(const bf16x8*)&Bhi_g[tbo + a1];
      bfl0 = *(const bf16x8*)&Blo_g[tbo + a0];
      bfl1 = *(const bf16x8*)&Blo_g[tbo + a1];
      const size_t qco = (size_t)t0 * 128;
      #pragma unroll
      for (int ks = 0; ks < 4; ++ks) {
        int ao = ar*128 + (((4*ks + quad) ^ arx) << 3);
        qfh[ks] = *(const bf16x8*)&qh[qco + ao];
        qfl[ks] = *(const bf16x8*)&qlp[qco + ao];
      }
    }

    f32x4 facc = (f32x4){0.f,0.f,0.f,0.f};
    if (ch) {
      f32x4 f2 = (f32x4){0.f,0.f,0.f,0.f};
      #pragma unroll
      for (int ks = 0; ks < 4; ++ks) {
        const int u = 4*ks + quad;
        const int bo = v16*128 + ((u ^ vx) << 3);
        bf16x8 bhi = *(const bf16x8*)&S0h[bo];
        bf16x8 blo = *(const bf16x8*)&S0l[bo];
        bf16x8 ahi, alo;
        if (!isQ) {
          const int ao = ar*128 + ((u ^ arx) << 3);
          ahi = *(const bf16x8*)&KhiL[cur][ao];
          alo = *(const bf16x8*)&KloL[cur][ao];
        } else {
          ahi = qfh[ks]; alo = qfl[ks];
        }
        facc = MFMA16(ahi, bhi, facc);
        f2   = MFMA16(ahi, blo, f2);
        f2   = MFMA16(alo, bhi, f2);
      }
      facc[0] += f2[0]; facc[1] += f2[1]; facc[2] += f2[2]; facc[3] += f2[3];
    }
    const int t4 = tb + quad*4;
    const int wo = v16*64 + ((((t4>>3) ^ vx)) << 3) + (t4 & 7);
    f32x4 qacc = facc;
    if (!isQ) {
      float xr[4];
      #pragma unroll
      for (int r = 0; r < 4; ++r) {
        const int t = t4 + r;
        float be = __shfl(bv, t);
        float ga = __expf(__shfl(gv, t));
        float vvv = vg[(size_t)(t0 + t)*128 + v16];
        xr[r] = fmaf(-be*ga, facc[r], be*vvv);
      }
      ushort4 h4, l4;
      h4.x = f2bf(xr[0]); h4.y = f2bf(xr[1]); h4.z = f2bf(xr[2]); h4.w = f2bf(xr[3]);
      l4.x = f2bf(xr[0]-bfu2f(h4.x)); l4.y = f2bf(xr[1]-bfu2f(h4.y));
      l4.z = f2bf(xr[2]-bfu2f(h4.z)); l4.w = f2bf(xr[3]-bfu2f(h4.w));
      *(ushort4*)&WTh[wo] = h4;
      *(ushort4*)&WTl[wo] = l4;
    }
    __syncthreads();

    if (!isQ) {
      f32x4 wa = (f32x4){0.f,0.f,0.f,0.f};
      f32x4 wb = (f32x4){0.f,0.f,0.f,0.f};
      {
        const int b0 = v16*64 + ((quad ^ vx) << 3);
        const int b1 = v16*64 + (((4 + quad) ^ vx) << 3);
        bf16x8 r0h = *(const bf16x8*)&WTh[b0];
        bf16x8 r0l = *(const bf16x8*)&WTl[b0];
        bf16x8 r1h = *(const bf16x8*)&WTh[b1];
        bf16x8 r1l = *(const bf16x8*)&WTl[b1];
        wa = MFMA16(tfh0, r0h, wa);
        wb = MFMA16(tfh0, r0l, wb);
        wb = MFMA16(tfl0, r0h, wb);
        wa = MFMA16(tfh1, r1h, wa);
        wb = MFMA16(tfh1, r1l, wb);
        wb = MFMA16(tfl1, r1h, wb);
      }
      float Le = __shfl(gv, 63);
      float x0 = wa[0]+wb[0], x1 = wa[1]+wb[1], x2 = wa[2]+wb[2], x3 = wa[3]+wb[3];
      ushort4 h4, l4;
      h4.x = f2bf(x0); h4.y = f2bf(x1); h4.z = f2bf(x2); h4.w = f2bf(x3);
      l4.x = f2bf(x0-bfu2f(h4.x)); l4.y = f2bf(x1-bfu2f(h4.y));
      l4.z = f2bf(x2-bfu2f(h4.z)); l4.w = f2bf(x3-bfu2f(h4.w));
      *(ushort4*)&W2Th[wo] = h4;
      *(ushort4*)&W2Tl[wo] = l4;
      float w30 = x0 * __expf(Le - __shfl(gv, t4+0));
      float w31 = x1 * __expf(Le - __shfl(gv, t4+1));
      float w32 = x2 * __expf(Le - __shfl(gv, t4+2));
      float w33 = x3 * __expf(Le - __shfl(gv, t4+3));
      ushort4 h3, l3;
      h3.x = f2bf(w30); h3.y = f2bf(w31); h3.z = f2bf(w32); h3.w = f2bf(w33);
      l3.x = f2bf(w30-bfu2f(h3.x)); l3.y = f2bf(w31-bfu2f(h3.y));
      l3.z = f2bf(w32-bfu2f(h3.z)); l3.w = f2bf(w33-bfu2f(h3.w));
      *(ushort4*)&W3Th[wo] = h3;
      *(ushort4*)&W3Tl[wo] = l3;
    }
    __syncthreads();

    if (isQ) {
      f32x4 oa = (f32x4){0.f,0.f,0.f,0.f};
      f32x4 ob2 = (f32x4){0.f,0.f,0.f,0.f};
      const int b0 = v16*64 + ((quad ^ vx) << 3);
      const int b1 = v16*64 + (((4 + quad) ^ vx) << 3);
      bf16x8 w0h = *(const bf16x8*)&W2Th[b0];
      bf16x8 w0l = *(const bf16x8*)&W2Tl[b0];
      bf16x8 w1h = *(const bf16x8*)&W2Th[b1];
      bf16x8 w1l = *(const bf16x8*)&W2Tl[b1];
      oa  = MFMA16(bfh0, w0h, oa);
      ob2 = MFMA16(bfh0, w0l, ob2);
      ob2 = MFMA16(bfl0, w0h, ob2);
      oa  = MFMA16(bfh1, w1h, oa);
      ob2 = MFMA16(bfh1, w1l, ob2);
      ob2 = MFMA16(bfl1, w1h, ob2);
      #pragma unroll
      for (int r = 0; r < 4; ++r) {
        const int t = t4 + r;
        float ga = __expf(__shfl(gv, t));
        og[(size_t)(t0 + t)*128 + v16] = fmaf(ga, qacc[r], oa[r] + ob2[r]);
      }
    }

    if (ch != 15) {
      float gC = __expf(__shfl(gv, 63));
      sreg[0] *= gC; sreg[1] *= gC; sreg[2] *= gC; sreg[3] *= gC;
      f32x4 s2 = (f32x4){0.f,0.f,0.f,0.f};
      #pragma unroll
      for (int ks = 0; ks < 2; ++ks) {
        const int u = 4*ks + quad;
        const int tbase = u * 8;
        bf16x8 ahi, alo;
        #pragma unroll
        for (int j = 0; j < 8; ++j) {
          const int ad = (tbase + j)*128 + ((k8 ^ j) << 3) + k7;
          ahi[j] = *(const __bf16*)&KhiL[cur][ad];
          alo[j] = *(const __bf16*)&KloL[cur][ad];
        }
        const int bo = v16*64 + ((u ^ vx) << 3);
        bf16x8 bhi = *(const bf16x8*)&W3Th[bo];
        bf16x8 blo = *(const bf16x8*)&W3Tl[bo];
        sreg = MFMA16(ahi, bhi, sreg);
        s2   = MFMA16(ahi, blo, s2);
        s2   = MFMA16(alo, bhi, s2);
      }
      sreg[0] += s2[0]; sreg[1] += s2[1]; sreg[2] += s2[2]; sreg[3] += s2[3];
      const int so = v16*128 + ((kr8 ^ vx) << 3) + kq4;
      ushort4 h4, l4;
      h4.x = f2bf(sreg[0]); h4.y = f2bf(sreg[1]);
      h4.z = f2bf(sreg[2]); h4.w = f2bf(sreg[3]);
      l4.x = f2bf(sreg[0]-bfu2f(h4.x)); l4.y = f2bf(sreg[1]-bfu2f(h4.y));
      l4.z = f2bf(sreg[2]-bfu2f(h4.z)); l4.w = f2bf(sreg[3]-bfu2f(h4.w));
      *(ushort4*)&S0h[so] = h4;
      *(ushort4*)&S0l[so] = l4;
    }
  }
}

// rmsnorm(o)*norm_w*silu(z) -> bf16 og; z bf16.
// 256 threads = 4 rows/block.
__global__ __launch_bounds__(256) void gnorm_kernel(
    const float* __restrict__ ob, const unsigned short* __restrict__ zbb,
    const float* __restrict__ norm_w, unsigned short* __restrict__ og) {
  const int tid = threadIdx.x;
  const int idx = blockIdx.x * 4 + (tid >> 6);
  const int lane = tid & 63;
  const int t = idx & 1023;
  const int bh = idx >> 10;
  const int b = bh >> 3;
  const int h = bh & 7;
  const float* o = ob + ((size_t)bh*T_ + t)*128;
  float2 ov = *(const float2*)(o + lane*2);
  float ss = fmaf(ov.x, ov.x, ov.y*ov.y);
  #pragma unroll
  for (int m=1; m<64; m<<=1) ss += __shfl_xor(ss, m);
  float inv = rsqrtf(ss*(1.f/128.f) + 1e-6f);
  size_t zoff = ((size_t)(b*T_+t))*1024 + (size_t)h*128 + lane*2;
  ushort2 zv = *(const ushort2*)(zbb + zoff);
  float z0 = bfu2f(zv.x), z1 = bfu2f(zv.y);
  float n0 = norm_w[lane*2], n1 = norm_w[lane*2+1];
  float r0 = ov.x*inv*n0 * z0/(1.f+expf(-z0));
  float r1 = ov.y*inv*n1 * z1/(1.f+expf(-z1));
  ushort2 ot;
  ot.x = f2bf(r0); ot.y = f2bf(r1);
  *(ushort2*)(og + zoff) = ot;
}

extern "C" void kernel_launch(void* const* d_in, const int* in_sizes, int n_in,
                              void* d_out, int out_size, void* d_ws, size_t ws_size,
                              hipStream_t stream) {
  const float* hs     = (const float*)d_in[0];
  const float* qkv_w  = (const float*)d_in[1];
  const float* z_w    = (const float*)d_in[2];
  const float* b_w    = (const float*)d_in[3];
  const float* a_w    = (const float*)d_in[4];
  const float* conv_w = (const float*)d_in[5];
  const float* dt_bias= (const float*)d_in[6];
  const float* A_log  = (const float*)d_in[7];
  const float* norm_w = (const float*)d_in[8];
  const float* out_w  = (const float*)d_in[9];
  float* out = (float*)d_out;

  char* wsp = (char*)d_ws;
  size_t off = 0;
  auto give = [&](size_t bytes)->char*{
    char* p = wsp + off; off += (bytes + 255) & ~(size_t)255; return p;
  };
  char* big    = give((size_t)MROWS*CONV_DIM_*4);            // 48 MB: k/q hi/lo + v
  unsigned short* zbuf = (unsigned short*)give((size_t)MROWS*1024*2);  // 8 MB
  unsigned short* outw_bf = (unsigned short*)give((size_t)HID_*1024*2); // 2 MB
  char* bufA   = give((size_t)32*T_*128*4);                  // 16 MB
  char* bufB   = give((size_t)32*T_*128*4);                  // 16 MB
  char* bufC   = give((size_t)32*T_*128*4);                  // 16 MB
  float* gbuf  = (float*)give((size_t)32*T_*4);
  float* beta  = (float*)give((size_t)32*T_*4);

  // big (48 MB): fused GEMM+conv outputs
  unsigned short* khi = (unsigned short*)big;                     // 8 MB
  unsigned short* klo = khi + (size_t)4*1024*1024;                // 8 MB
  unsigned short* qhi = klo + (size_t)4*1024*1024;                // 8 MB
  unsigned short* qlo = qhi + (size_t)4*1024*1024;                // 8 MB
  float* vdat = (float*)(qlo + (size_t)4*1024*1024);              // 16 MB
  // bufA: wz_bf [0,2MB) -> Blo [2,6MB) -> og [6,10MB); edge [10,12.25MB)
  unsigned short* wz_bf = (unsigned short*)bufA;
  unsigned short* Blo_g = (unsigned short*)bufA + (size_t)1024*1024;
  unsigned short* og    = (unsigned short*)bufA + (size_t)3*1024*1024;
  float* edge           = (float*)(bufA + (size_t)10*1024*1024);  // 2.25 MB
  // bufB: hs_hi/lo [0,16MB) -> Thi [0,4) Tlo [4,8) Bhi [8,12)
  unsigned short* hs_hi = (unsigned short*)bufB;
  unsigned short* hs_lo = hs_hi + (size_t)MROWS*HID_;
  unsigned short* Thi_g = (unsigned short*)bufB;
  unsigned short* Tlo_g = Thi_g + (size_t)512*4096;
  unsigned short* Bhi_g = Tlo_g + (size_t)512*4096;
  // bufC: wc_hi/lo [0,12.6MB) -> ob [0,16MB)
  unsigned short* wc_hi = (unsigned short*)bufC;
  unsigned short* wc_lo = wc_hi + (size_t)CONV_DIM_*HID_;
  float* ob = (float*)bufC;

  prep_kernel<<<dim3(5120 + MROWS/2), 256, 0, stream>>>(
      qkv_w, z_w, out_w, wc_hi, wc_lo, wz_bf, outw_bf,
      hs, b_w, a_w, dt_bias, A_log, gbuf, beta, hs_hi, hs_lo);
  gemm_split_conv_kernel<<<dim3(32, MROWS/128), 256, 0, stream>>>(
      hs_hi, hs_lo, wc_hi, wc_lo, wz_bf, conv_w, qhi, qlo, khi, klo, vdat, edge, zbuf);
  conv_fix_kernel<<<dim3(32*24), dim3(128), 0, stream>>>(
      edge, conv_w, qhi, qlo, khi, klo, vdat);
  scan_ab_kernel<<<dim3(512), dim3(256), 0, stream>>>(
      qhi, qlo, khi, klo, gbuf, beta, Thi_g, Tlo_g, Bhi_g, Blo_g);
  scan_seq_kernel<<<dim3(256), dim3(512), 0, stream>>>(
      khi, klo, qhi, qlo, vdat, gbuf, beta, Thi_g, Tlo_g, Bhi_g, Blo_g, ob);
  gnorm_kernel<<<dim3(32*T_/4), dim3(256), 0, stream>>>(ob, zbuf, norm_w, og);
  gemm_mfma_kernel<0><<<dim3(1024/128, MROWS/128), 256, 0, stream>>>(og, outw_bf, out, MROWS, 1024, HID_);
}